// Round 1
// baseline (1377.199 us; speedup 1.0000x reference)
//
#include <hip/hip_runtime.h>
#include <hip/hip_bf16.h>

// GCN: N=100000 nodes, E=1600000 edges, B=64 graphs, 20 -> 128 -> 128 -> 256.
// Strategy:
//  - gcn_conv(h,W) = (scatter_norm(h)) @ W   (linearity) -> aggregate BEFORE the
//    transform: conv1 gathers in 20-dim, conv3 gathers in 128-dim, and the
//    mean-pool also happens BEFORE the final W3 GEMM (pool commutes with W3).
//  - Build CSR (grouped by dst) per launch: count -> scan -> fill. Gathers are
//    then atomic-free: one wave per node, float2 per lane.
//  - conv2: fused LDS-tiled 128x128 fp32 GEMM with bias + residual add, in-place.

constexpr int N  = 100000;
constexpr int E  = 1600000;
constexpr int B  = 64;
constexpr int IND = 20;
constexpr int HID = 128;
constexpr int OUTD = 256;
constexpr int NCHUNK = (N + 1023) / 1024;   // 98 scan chunks

// ---------------- CSR build ----------------

__global__ __launch_bounds__(256) void k_init(int* __restrict__ indeg,
                                              int* __restrict__ starts,
                                              float* __restrict__ pooled) {
  int i = blockIdx.x * 256 + threadIdx.x;
  if (i < N) indeg[i] = 0;
  if (i <= B) starts[i] = 0x7fffffff;
  if (i < B * HID) pooled[i] = 0.f;
}

__global__ __launch_bounds__(256) void k_count(const int* __restrict__ eidx,
                                               int* __restrict__ indeg) {
  int e = blockIdx.x * 256 + threadIdx.x;           // grid exactly E/256
  atomicAdd(&indeg[eidx[E + e]], 1);
}

__global__ __launch_bounds__(256) void k_starts(const int* __restrict__ batch,
                                                int* __restrict__ starts) {
  int i = blockIdx.x * 256 + threadIdx.x;
  if (i < N) atomicMin(&starts[batch[i]], i);
}

__global__ void k_fix_starts(int* starts) {
  starts[B] = N;
  for (int g = B - 1; g >= 0; --g)
    if (starts[g] == 0x7fffffff) starts[g] = starts[g + 1];
}

__global__ __launch_bounds__(256) void k_scan1(const int* __restrict__ indeg,
                                               int* __restrict__ rowptr,
                                               int* __restrict__ csums) {
  __shared__ int s[256];
  int tid = threadIdx.x;
  long base = (long)blockIdx.x * 1024 + (long)tid * 4;
  int v0 = (base + 0 < N) ? indeg[base + 0] : 0;
  int v1 = (base + 1 < N) ? indeg[base + 1] : 0;
  int v2 = (base + 2 < N) ? indeg[base + 2] : 0;
  int v3 = (base + 3 < N) ? indeg[base + 3] : 0;
  int p0 = v0, p1 = p0 + v1, p2 = p1 + v2, p3 = p2 + v3;
  s[tid] = p3;
  for (int off = 1; off < 256; off <<= 1) {
    __syncthreads();
    int x = (tid >= off) ? s[tid - off] : 0;
    __syncthreads();
    s[tid] += x;
  }
  int excl = s[tid] - p3;
  if (base + 0 < N) rowptr[base + 1] = excl + p0;
  if (base + 1 < N) rowptr[base + 2] = excl + p1;
  if (base + 2 < N) rowptr[base + 3] = excl + p2;
  if (base + 3 < N) rowptr[base + 4] = excl + p3;
  if (tid == 255) csums[blockIdx.x] = s[255];
}

__global__ __launch_bounds__(128) void k_scan2(int* __restrict__ csums) {
  __shared__ int s[128];
  int tid = threadIdx.x;
  int v = (tid < NCHUNK) ? csums[tid] : 0;
  s[tid] = v;
  for (int off = 1; off < 128; off <<= 1) {
    __syncthreads();
    int x = (tid >= off) ? s[tid - off] : 0;
    __syncthreads();
    s[tid] += x;
  }
  __syncthreads();
  if (tid < NCHUNK) csums[tid] = s[tid] - v;   // exclusive
}

__global__ __launch_bounds__(256) void k_scan3(const int* __restrict__ indeg,
                                               const int* __restrict__ csums,
                                               int* __restrict__ rowptr,
                                               float* __restrict__ dinv) {
  int i = blockIdx.x * 256 + threadIdx.x;
  if (i >= N) return;
  rowptr[i + 1] += csums[i >> 10];
  if (i == 0) rowptr[0] = 0;
  dinv[i] = rsqrtf((float)(1 + indeg[i]));     // deg includes self-loop
}

__global__ __launch_bounds__(256) void k_fill(const int* __restrict__ eidx,
                                              const int* __restrict__ rowptr,
                                              int* __restrict__ indeg,
                                              int* __restrict__ colsrc) {
  int e = blockIdx.x * 256 + threadIdx.x;           // grid exactly E/256
  int s = eidx[e];
  int d = eidx[E + e];
  int old = atomicSub(&indeg[d], 1);
  colsrc[rowptr[d] + old - 1] = s;
}

// ---------------- aggregation (atomic-free gathers) ----------------

// 20-dim gather of raw x: aggx[i] = x[i]*dinv^2 + sum_e x[src]*dinv[s]*dinv[i]
__global__ __launch_bounds__(256) void k_gather20(const float* __restrict__ x,
                                                  const float* __restrict__ dinv,
                                                  const int* __restrict__ rowptr,
                                                  const int* __restrict__ colsrc,
                                                  float* __restrict__ aggx) {
  int t = threadIdx.x;
  if (t >= 240) return;
  int n = t / IND, c = t % IND;
  long i = (long)blockIdx.x * 12 + n;
  if (i >= N) return;
  float di = dinv[i];
  float acc = x[i * IND + c] * di * di;
  int e0 = rowptr[i], e1 = rowptr[i + 1];
  for (int e = e0; e < e1; ++e) {
    int s = colsrc[e];
    acc += x[(long)s * IND + c] * dinv[s] * di;
  }
  aggx[i * IND + c] = acc;
}

// 128-dim gather: one wave per node, float2 per lane.
__global__ __launch_bounds__(256) void k_gather128(const float* __restrict__ t,
                                                   const float* __restrict__ dinv,
                                                   const int* __restrict__ rowptr,
                                                   const int* __restrict__ colsrc,
                                                   float* __restrict__ agg) {
  const int lane = threadIdx.x & 63;
  const long i = (long)blockIdx.x * 4 + (threadIdx.x >> 6);   // grid = N/4 exact
  const float di = dinv[i];
  const int c = lane * 2;
  float2 v = *(const float2*)&t[i * HID + c];
  float ax = v.x * di * di, ay = v.y * di * di;
  const int e0 = rowptr[i], e1 = rowptr[i + 1];
  for (int e = e0; e < e1; ++e) {
    const int s = colsrc[e];
    const float w = dinv[s] * di;
    float2 u = *(const float2*)&t[(long)s * HID + c];
    ax += u.x * w;
    ay += u.y * w;
  }
  *(float2*)&agg[i * HID + c] = make_float2(ax, ay);
}

// ---------------- dense layers ----------------

// T = aggx@W1 + b1 + x@res_W + res_b   (pre-LN1 sum), 16 nodes / block
__global__ __launch_bounds__(128) void k_conv1(const float* __restrict__ aggx,
                                               const float* __restrict__ x,
                                               const float* __restrict__ W1,
                                               const float* __restrict__ b1,
                                               const float* __restrict__ Wr,
                                               const float* __restrict__ rb,
                                               float* __restrict__ T) {
  __shared__ float W1s[IND * HID], Wrs[IND * HID], as[16 * IND], xs[16 * IND];
  int tid = threadIdx.x;
  for (int i = tid; i < IND * HID; i += 128) { W1s[i] = W1[i]; Wrs[i] = Wr[i]; }
  long node0 = (long)blockIdx.x * 16;                 // grid = N/16 exact
  for (int i = tid; i < 16 * IND; i += 128) {
    as[i] = aggx[node0 * IND + i];
    xs[i] = x[node0 * IND + i];
  }
  float bj = b1[tid] + rb[tid];
  __syncthreads();
  for (int n = 0; n < 16; ++n) {
    float a = bj;
#pragma unroll
    for (int k = 0; k < IND; ++k) {
      a = fmaf(as[n * IND + k], W1s[k * HID + tid], a);
      a = fmaf(xs[n * IND + k], Wrs[k * HID + tid], a);
    }
    T[(node0 + n) * HID + tid] = a;
  }
}

// out = in@W + bias + res   (128x128, K-tiled in LDS, 32 nodes / block, in-place safe)
__global__ __launch_bounds__(256) void k_gemm128(const float* in,
                                                 const float* __restrict__ W,
                                                 const float* __restrict__ bias,
                                                 const float* __restrict__ res,
                                                 float* out) {
  constexpr int NPB = 32;
  __shared__ float Wt[32 * HID];
  __shared__ float Xs[NPB * HID];
  const int tid = threadIdx.x;
  const long node0 = (long)blockIdx.x * NPB;          // grid = N/32 exact
  {
    const float4* sp = (const float4*)(in + node0 * HID);
    float4* dp = (float4*)Xs;
    for (int i = tid; i < NPB * HID / 4; i += 256) dp[i] = sp[i];
  }
  const int nidx = tid >> 5;          // 8 nodes in flight
  const int col = (tid & 31) * 4;     // 32 threads cover 128 cols
  float4 acc[4];
#pragma unroll
  for (int m = 0; m < 4; ++m) acc[m] = make_float4(0.f, 0.f, 0.f, 0.f);
  for (int kt = 0; kt < 4; ++kt) {
    __syncthreads();
    {
      const float4* wp = (const float4*)(W + kt * 32 * HID);
      float4* wd = (float4*)Wt;
      for (int i = tid; i < 32 * HID / 4; i += 256) wd[i] = wp[i];
    }
    __syncthreads();
#pragma unroll
    for (int k = 0; k < 32; k += 4) {
      float4 w[4];
#pragma unroll
      for (int kk = 0; kk < 4; ++kk) w[kk] = *(const float4*)&Wt[(k + kk) * HID + col];
#pragma unroll
      for (int m = 0; m < 4; ++m) {
        const int nm = nidx + m * 8;
        float4 x4 = *(const float4*)&Xs[nm * HID + kt * 32 + k];
        float xv[4] = {x4.x, x4.y, x4.z, x4.w};
#pragma unroll
        for (int kk = 0; kk < 4; ++kk) {
          acc[m].x = fmaf(xv[kk], w[kk].x, acc[m].x);
          acc[m].y = fmaf(xv[kk], w[kk].y, acc[m].y);
          acc[m].z = fmaf(xv[kk], w[kk].z, acc[m].z);
          acc[m].w = fmaf(xv[kk], w[kk].w, acc[m].w);
        }
      }
    }
  }
  float4 bz = *(const float4*)&bias[col];
#pragma unroll
  for (int m = 0; m < 4; ++m) {
    long nm = node0 + nidx + m * 8;
    float4 rz = *(const float4*)&res[nm * HID + col];
    float4 o = acc[m];
    o.x += bz.x + rz.x; o.y += bz.y + rz.y;
    o.z += bz.z + rz.z; o.w += bz.w + rz.w;
    *(float4*)&out[nm * HID + col] = o;
  }
}

// out = relu(layernorm(in)) , one wave per node
__global__ __launch_bounds__(256) void k_lnrelu(const float* __restrict__ in,
                                                const float* __restrict__ g,
                                                const float* __restrict__ b,
                                                float* __restrict__ out) {
  const int lane = threadIdx.x & 63;
  const long i = (long)blockIdx.x * 4 + (threadIdx.x >> 6);   // grid = N/4 exact
  const int c = lane * 2;
  float2 v = *(const float2*)&in[i * HID + c];
  float s = v.x + v.y, q = v.x * v.x + v.y * v.y;
#pragma unroll
  for (int off = 32; off; off >>= 1) {
    s += __shfl_xor(s, off);
    q += __shfl_xor(q, off);
  }
  const float mu = s * (1.f / 128.f);
  const float var = q * (1.f / 128.f) - mu * mu;
  const float rs = rsqrtf(var + 1e-5f);
  float2 gg = *(const float2*)&g[c], bb = *(const float2*)&b[c];
  float y0 = fmaxf(fmaf((v.x - mu) * rs, gg.x, bb.x), 0.f);
  float y1 = fmaxf(fmaf((v.y - mu) * rs, gg.y, bb.y), 0.f);
  *(float2*)&out[i * HID + c] = make_float2(y0, y1);
}

// ---------------- pooling + final GEMM ----------------

__global__ __launch_bounds__(128) void k_pool(const float* __restrict__ agg,
                                              const int* __restrict__ starts,
                                              float* __restrict__ pooled) {
  int g = blockIdx.x >> 3, part = blockIdx.x & 7;
  int s0 = starts[g], s1 = starts[g + 1];
  int len = s1 - s0;
  int chunk = (len + 7) >> 3;
  int a = s0 + part * chunk;
  int bnd = min(a + chunk, s1);
  if (a >= bnd) return;
  float acc = 0.f;
  for (long i = a; i < bnd; ++i) acc += agg[i * HID + threadIdx.x];
  atomicAdd(&pooled[g * HID + threadIdx.x], acc);
}

// out[g] = (pooled[g]/cnt) @ W3 + b3
__global__ __launch_bounds__(256) void k_final(const float* __restrict__ pooled,
                                               const int* __restrict__ starts,
                                               const float* __restrict__ W3,
                                               const float* __restrict__ b3,
                                               float* __restrict__ out) {
  __shared__ float p[HID];
  int g = blockIdx.x, tid = threadIdx.x;
  int len = starts[g + 1] - starts[g];
  float scale = 1.0f / fmaxf((float)len, 1.0f);
  if (tid < HID) p[tid] = pooled[g * HID + tid] * scale;
  __syncthreads();
  float a = b3[tid];
  for (int k = 0; k < HID; ++k) a = fmaf(p[k], W3[k * OUTD + tid], a);
  out[g * OUTD + tid] = a;
}

// ---------------- launch ----------------

extern "C" void kernel_launch(void* const* d_in, const int* in_sizes, int n_in,
                              void* d_out, int out_size, void* d_ws, size_t ws_size,
                              hipStream_t stream) {
  const float* x    = (const float*)d_in[0];
  const int*   eidx = (const int*)d_in[1];
  const int*   batch= (const int*)d_in[2];
  const float* W1   = (const float*)d_in[3];
  const float* b1   = (const float*)d_in[4];
  const float* W2   = (const float*)d_in[5];
  const float* b2   = (const float*)d_in[6];
  const float* W3   = (const float*)d_in[7];
  const float* b3   = (const float*)d_in[8];
  const float* resW = (const float*)d_in[9];
  const float* resb = (const float*)d_in[10];
  const float* g1   = (const float*)d_in[11];
  const float* bb1  = (const float*)d_in[12];
  const float* g2   = (const float*)d_in[13];
  const float* bb2  = (const float*)d_in[14];
  float* out = (float*)d_out;

  char* w = (char*)d_ws;
  size_t off = 0;
  auto alloc = [&](size_t bytes) {
    char* p = w + off;
    off = (off + bytes + 1023) & ~(size_t)1023;
    return p;
  };
  float* dinv   = (float*)alloc((size_t)N * 4);
  int*   indeg  = (int*)alloc((size_t)N * 4);
  int*   rowptr = (int*)alloc((size_t)(N + 1) * 4);
  int*   colsrc = (int*)alloc((size_t)E * 4);
  int*   starts = (int*)alloc((size_t)(B + 1) * 4);
  int*   csums  = (int*)alloc((size_t)NCHUNK * 4);
  float* pooled = (float*)alloc((size_t)B * HID * 4);
  float* aggx   = (float*)alloc((size_t)N * IND * 4);
  float* hbuf   = (float*)alloc((size_t)N * HID * 4);
  float* aggh   = (float*)alloc((size_t)N * HID * 4);

  // ---- CSR + norm + segment starts ----
  k_init<<<(N + 255) / 256, 256, 0, stream>>>(indeg, starts, pooled);
  k_count<<<E / 256, 256, 0, stream>>>(eidx, indeg);
  k_starts<<<(N + 255) / 256, 256, 0, stream>>>(batch, starts);
  k_scan1<<<NCHUNK, 256, 0, stream>>>(indeg, rowptr, csums);
  k_scan2<<<1, 128, 0, stream>>>(csums);
  k_scan3<<<(N + 255) / 256, 256, 0, stream>>>(indeg, csums, rowptr, dinv);
  k_fix_starts<<<1, 1, 0, stream>>>(starts);
  k_fill<<<E / 256, 256, 0, stream>>>(eidx, rowptr, indeg, colsrc);

  // ---- layer 1: aggregate x (20-dim), transform+bias+residual, LN+relu ----
  k_gather20<<<(N + 11) / 12, 256, 0, stream>>>(x, dinv, rowptr, colsrc, aggx);
  k_conv1<<<N / 16, 128, 0, stream>>>(aggx, x, W1, b1, resW, resb, aggh);
  k_lnrelu<<<N / 4, 256, 0, stream>>>(aggh, g1, bb1, hbuf);       // h1

  // ---- layer 2: aggregate h1, GEMM(+b2+residual h1) in-place, LN+relu ----
  k_gather128<<<N / 4, 256, 0, stream>>>(hbuf, dinv, rowptr, colsrc, aggh);
  k_gemm128<<<N / 32, 256, 0, stream>>>(aggh, W2, b2, hbuf, aggh);
  k_lnrelu<<<N / 4, 256, 0, stream>>>(aggh, g2, bb2, hbuf);       // h2

  // ---- layer 3: aggregate h2 (128-dim), pool, then tiny GEMM to 256 ----
  k_gather128<<<N / 4, 256, 0, stream>>>(hbuf, dinv, rowptr, colsrc, aggh);
  k_pool<<<B * 8, 128, 0, stream>>>(aggh, starts, pooled);
  k_final<<<B, 256, 0, stream>>>(pooled, starts, W3, b3, out);
}

// Round 2
// 850.815 us; speedup vs baseline: 1.6187x; 1.6187x over previous
//
#include <hip/hip_runtime.h>
#include <hip/hip_bf16.h>

// GCN: N=100000 nodes, E=1600000 edges, B=64 graphs, 20 -> 128 -> 128 -> 256.
// Strategy:
//  - gcn_conv(h,W) = (scatter_norm(h)) @ W   (linearity) -> aggregate BEFORE the
//    transform: conv1 gathers in 20-dim, conv3 gathers in 128-dim, and the
//    mean-pool also happens BEFORE the final W3 GEMM (pool commutes with W3).
//  - Build CSR (grouped by dst) per launch: count -> scan -> fill. Gathers are
//    then atomic-free: one wave per node, float2 per lane.
//  - conv2: fused LDS-tiled 128x128 fp32 GEMM with bias + residual add, in-place.
//  - R1: segment starts via sorted-batch boundary detection (plain stores).
//    R0's atomicMin over 64 slots serialized -> 520 us alone.

constexpr int N  = 100000;
constexpr int E  = 1600000;
constexpr int B  = 64;
constexpr int IND = 20;
constexpr int HID = 128;
constexpr int OUTD = 256;
constexpr int NCHUNK = (N + 1023) / 1024;   // 98 scan chunks

// ---------------- CSR build ----------------

__global__ __launch_bounds__(256) void k_init(int* __restrict__ indeg,
                                              float* __restrict__ pooled) {
  int i = blockIdx.x * 256 + threadIdx.x;
  if (i < N) indeg[i] = 0;
  if (i < B * HID) pooled[i] = 0.f;
}

__global__ __launch_bounds__(256) void k_count(const int* __restrict__ eidx,
                                               int* __restrict__ indeg) {
  int e = blockIdx.x * 256 + threadIdx.x;           // grid exactly E/256
  atomicAdd(&indeg[eidx[E + e]], 1);
}

// batch is sorted: boundary threads plain-store segment starts. No atomics.
__global__ __launch_bounds__(256) void k_seg_starts(const int* __restrict__ batch,
                                                    int* __restrict__ starts) {
  int i = blockIdx.x * 256 + threadIdx.x;
  if (i >= N) return;
  int b = batch[i];
  int prev = (i == 0) ? -1 : batch[i - 1];
  for (int g = prev + 1; g <= b; ++g) starts[g] = i;  // fires only at boundaries
  if (i == N - 1)
    for (int g = b + 1; g <= B; ++g) starts[g] = N;
}

__global__ __launch_bounds__(256) void k_scan1(const int* __restrict__ indeg,
                                               int* __restrict__ rowptr,
                                               int* __restrict__ csums) {
  __shared__ int s[256];
  int tid = threadIdx.x;
  long base = (long)blockIdx.x * 1024 + (long)tid * 4;
  int v0 = (base + 0 < N) ? indeg[base + 0] : 0;
  int v1 = (base + 1 < N) ? indeg[base + 1] : 0;
  int v2 = (base + 2 < N) ? indeg[base + 2] : 0;
  int v3 = (base + 3 < N) ? indeg[base + 3] : 0;
  int p0 = v0, p1 = p0 + v1, p2 = p1 + v2, p3 = p2 + v3;
  s[tid] = p3;
  for (int off = 1; off < 256; off <<= 1) {
    __syncthreads();
    int x = (tid >= off) ? s[tid - off] : 0;
    __syncthreads();
    s[tid] += x;
  }
  int excl = s[tid] - p3;
  if (base + 0 < N) rowptr[base + 1] = excl + p0;
  if (base + 1 < N) rowptr[base + 2] = excl + p1;
  if (base + 2 < N) rowptr[base + 3] = excl + p2;
  if (base + 3 < N) rowptr[base + 4] = excl + p3;
  if (tid == 255) csums[blockIdx.x] = s[255];
}

__global__ __launch_bounds__(128) void k_scan2(int* __restrict__ csums) {
  __shared__ int s[128];
  int tid = threadIdx.x;
  int v = (tid < NCHUNK) ? csums[tid] : 0;
  s[tid] = v;
  for (int off = 1; off < 128; off <<= 1) {
    __syncthreads();
    int x = (tid >= off) ? s[tid - off] : 0;
    __syncthreads();
    s[tid] += x;
  }
  __syncthreads();
  if (tid < NCHUNK) csums[tid] = s[tid] - v;   // exclusive
}

__global__ __launch_bounds__(256) void k_scan3(const int* __restrict__ indeg,
                                               const int* __restrict__ csums,
                                               int* __restrict__ rowptr,
                                               float* __restrict__ dinv) {
  int i = blockIdx.x * 256 + threadIdx.x;
  if (i >= N) return;
  rowptr[i + 1] += csums[i >> 10];
  if (i == 0) rowptr[0] = 0;
  dinv[i] = rsqrtf((float)(1 + indeg[i]));     // deg includes self-loop
}

__global__ __launch_bounds__(256) void k_fill(const int* __restrict__ eidx,
                                              const int* __restrict__ rowptr,
                                              int* __restrict__ indeg,
                                              int* __restrict__ colsrc) {
  int e = blockIdx.x * 256 + threadIdx.x;           // grid exactly E/256
  int s = eidx[e];
  int d = eidx[E + e];
  int old = atomicSub(&indeg[d], 1);
  colsrc[rowptr[d] + old - 1] = s;
}

// ---------------- aggregation (atomic-free gathers) ----------------

// 20-dim gather of raw x: aggx[i] = x[i]*dinv^2 + sum_e x[src]*dinv[s]*dinv[i]
__global__ __launch_bounds__(256) void k_gather20(const float* __restrict__ x,
                                                  const float* __restrict__ dinv,
                                                  const int* __restrict__ rowptr,
                                                  const int* __restrict__ colsrc,
                                                  float* __restrict__ aggx) {
  int t = threadIdx.x;
  if (t >= 240) return;
  int n = t / IND, c = t % IND;
  long i = (long)blockIdx.x * 12 + n;
  if (i >= N) return;
  float di = dinv[i];
  float acc = x[i * IND + c] * di * di;
  int e0 = rowptr[i], e1 = rowptr[i + 1];
  for (int e = e0; e < e1; ++e) {
    int s = colsrc[e];
    acc += x[(long)s * IND + c] * dinv[s] * di;
  }
  aggx[i * IND + c] = acc;
}

// 128-dim gather: one wave per node, float2 per lane.
__global__ __launch_bounds__(256) void k_gather128(const float* __restrict__ t,
                                                   const float* __restrict__ dinv,
                                                   const int* __restrict__ rowptr,
                                                   const int* __restrict__ colsrc,
                                                   float* __restrict__ agg) {
  const int lane = threadIdx.x & 63;
  const long i = (long)blockIdx.x * 4 + (threadIdx.x >> 6);   // grid = N/4 exact
  const float di = dinv[i];
  const int c = lane * 2;
  float2 v = *(const float2*)&t[i * HID + c];
  float ax = v.x * di * di, ay = v.y * di * di;
  const int e0 = rowptr[i], e1 = rowptr[i + 1];
  for (int e = e0; e < e1; ++e) {
    const int s = colsrc[e];
    const float w = dinv[s] * di;
    float2 u = *(const float2*)&t[(long)s * HID + c];
    ax += u.x * w;
    ay += u.y * w;
  }
  *(float2*)&agg[i * HID + c] = make_float2(ax, ay);
}

// ---------------- dense layers ----------------

// T = aggx@W1 + b1 + x@res_W + res_b   (pre-LN1 sum), 16 nodes / block
__global__ __launch_bounds__(128) void k_conv1(const float* __restrict__ aggx,
                                               const float* __restrict__ x,
                                               const float* __restrict__ W1,
                                               const float* __restrict__ b1,
                                               const float* __restrict__ Wr,
                                               const float* __restrict__ rb,
                                               float* __restrict__ T) {
  __shared__ float W1s[IND * HID], Wrs[IND * HID], as[16 * IND], xs[16 * IND];
  int tid = threadIdx.x;
  for (int i = tid; i < IND * HID; i += 128) { W1s[i] = W1[i]; Wrs[i] = Wr[i]; }
  long node0 = (long)blockIdx.x * 16;                 // grid = N/16 exact
  for (int i = tid; i < 16 * IND; i += 128) {
    as[i] = aggx[node0 * IND + i];
    xs[i] = x[node0 * IND + i];
  }
  float bj = b1[tid] + rb[tid];
  __syncthreads();
  for (int n = 0; n < 16; ++n) {
    float a = bj;
#pragma unroll
    for (int k = 0; k < IND; ++k) {
      a = fmaf(as[n * IND + k], W1s[k * HID + tid], a);
      a = fmaf(xs[n * IND + k], Wrs[k * HID + tid], a);
    }
    T[(node0 + n) * HID + tid] = a;
  }
}

// out = in@W + bias + res   (128x128, K-tiled in LDS, 32 nodes / block, in-place safe)
__global__ __launch_bounds__(256) void k_gemm128(const float* in,
                                                 const float* __restrict__ W,
                                                 const float* __restrict__ bias,
                                                 const float* __restrict__ res,
                                                 float* out) {
  constexpr int NPB = 32;
  __shared__ float Wt[32 * HID];
  __shared__ float Xs[NPB * HID];
  const int tid = threadIdx.x;
  const long node0 = (long)blockIdx.x * NPB;          // grid = N/32 exact
  {
    const float4* sp = (const float4*)(in + node0 * HID);
    float4* dp = (float4*)Xs;
    for (int i = tid; i < NPB * HID / 4; i += 256) dp[i] = sp[i];
  }
  const int nidx = tid >> 5;          // 8 nodes in flight
  const int col = (tid & 31) * 4;     // 32 threads cover 128 cols
  float4 acc[4];
#pragma unroll
  for (int m = 0; m < 4; ++m) acc[m] = make_float4(0.f, 0.f, 0.f, 0.f);
  for (int kt = 0; kt < 4; ++kt) {
    __syncthreads();
    {
      const float4* wp = (const float4*)(W + kt * 32 * HID);
      float4* wd = (float4*)Wt;
      for (int i = tid; i < 32 * HID / 4; i += 256) wd[i] = wp[i];
    }
    __syncthreads();
#pragma unroll
    for (int k = 0; k < 32; k += 4) {
      float4 w[4];
#pragma unroll
      for (int kk = 0; kk < 4; ++kk) w[kk] = *(const float4*)&Wt[(k + kk) * HID + col];
#pragma unroll
      for (int m = 0; m < 4; ++m) {
        const int nm = nidx + m * 8;
        float4 x4 = *(const float4*)&Xs[nm * HID + kt * 32 + k];
        float xv[4] = {x4.x, x4.y, x4.z, x4.w};
#pragma unroll
        for (int kk = 0; kk < 4; ++kk) {
          acc[m].x = fmaf(xv[kk], w[kk].x, acc[m].x);
          acc[m].y = fmaf(xv[kk], w[kk].y, acc[m].y);
          acc[m].z = fmaf(xv[kk], w[kk].z, acc[m].z);
          acc[m].w = fmaf(xv[kk], w[kk].w, acc[m].w);
        }
      }
    }
  }
  float4 bz = *(const float4*)&bias[col];
#pragma unroll
  for (int m = 0; m < 4; ++m) {
    long nm = node0 + nidx + m * 8;
    float4 rz = *(const float4*)&res[nm * HID + col];
    float4 o = acc[m];
    o.x += bz.x + rz.x; o.y += bz.y + rz.y;
    o.z += bz.z + rz.z; o.w += bz.w + rz.w;
    *(float4*)&out[nm * HID + col] = o;
  }
}

// out = relu(layernorm(in)) , one wave per node
__global__ __launch_bounds__(256) void k_lnrelu(const float* __restrict__ in,
                                                const float* __restrict__ g,
                                                const float* __restrict__ b,
                                                float* __restrict__ out) {
  const int lane = threadIdx.x & 63;
  const long i = (long)blockIdx.x * 4 + (threadIdx.x >> 6);   // grid = N/4 exact
  const int c = lane * 2;
  float2 v = *(const float2*)&in[i * HID + c];
  float s = v.x + v.y, q = v.x * v.x + v.y * v.y;
#pragma unroll
  for (int off = 32; off; off >>= 1) {
    s += __shfl_xor(s, off);
    q += __shfl_xor(q, off);
  }
  const float mu = s * (1.f / 128.f);
  const float var = q * (1.f / 128.f) - mu * mu;
  const float rs = rsqrtf(var + 1e-5f);
  float2 gg = *(const float2*)&g[c], bb = *(const float2*)&b[c];
  float y0 = fmaxf(fmaf((v.x - mu) * rs, gg.x, bb.x), 0.f);
  float y1 = fmaxf(fmaf((v.y - mu) * rs, gg.y, bb.y), 0.f);
  *(float2*)&out[i * HID + c] = make_float2(y0, y1);
}

// ---------------- pooling + final GEMM ----------------

__global__ __launch_bounds__(128) void k_pool(const float* __restrict__ agg,
                                              const int* __restrict__ starts,
                                              float* __restrict__ pooled) {
  int g = blockIdx.x >> 3, part = blockIdx.x & 7;
  int s0 = starts[g], s1 = starts[g + 1];
  int len = s1 - s0;
  int chunk = (len + 7) >> 3;
  int a = s0 + part * chunk;
  int bnd = min(a + chunk, s1);
  if (a >= bnd) return;
  float acc = 0.f;
  for (long i = a; i < bnd; ++i) acc += agg[i * HID + threadIdx.x];
  atomicAdd(&pooled[g * HID + threadIdx.x], acc);
}

// out[g] = (pooled[g]/cnt) @ W3 + b3
__global__ __launch_bounds__(256) void k_final(const float* __restrict__ pooled,
                                               const int* __restrict__ starts,
                                               const float* __restrict__ W3,
                                               const float* __restrict__ b3,
                                               float* __restrict__ out) {
  __shared__ float p[HID];
  int g = blockIdx.x, tid = threadIdx.x;
  int len = starts[g + 1] - starts[g];
  float scale = 1.0f / fmaxf((float)len, 1.0f);
  if (tid < HID) p[tid] = pooled[g * HID + tid] * scale;
  __syncthreads();
  float a = b3[tid];
  for (int k = 0; k < HID; ++k) a = fmaf(p[k], W3[k * OUTD + tid], a);
  out[g * OUTD + tid] = a;
}

// ---------------- launch ----------------

extern "C" void kernel_launch(void* const* d_in, const int* in_sizes, int n_in,
                              void* d_out, int out_size, void* d_ws, size_t ws_size,
                              hipStream_t stream) {
  const float* x    = (const float*)d_in[0];
  const int*   eidx = (const int*)d_in[1];
  const int*   batch= (const int*)d_in[2];
  const float* W1   = (const float*)d_in[3];
  const float* b1   = (const float*)d_in[4];
  const float* W2   = (const float*)d_in[5];
  const float* b2   = (const float*)d_in[6];
  const float* W3   = (const float*)d_in[7];
  const float* b3   = (const float*)d_in[8];
  const float* resW = (const float*)d_in[9];
  const float* resb = (const float*)d_in[10];
  const float* g1   = (const float*)d_in[11];
  const float* bb1  = (const float*)d_in[12];
  const float* g2   = (const float*)d_in[13];
  const float* bb2  = (const float*)d_in[14];
  float* out = (float*)d_out;

  char* w = (char*)d_ws;
  size_t off = 0;
  auto alloc = [&](size_t bytes) {
    char* p = w + off;
    off = (off + bytes + 1023) & ~(size_t)1023;
    return p;
  };
  float* dinv   = (float*)alloc((size_t)N * 4);
  int*   indeg  = (int*)alloc((size_t)N * 4);
  int*   rowptr = (int*)alloc((size_t)(N + 1) * 4);
  int*   colsrc = (int*)alloc((size_t)E * 4);
  int*   starts = (int*)alloc((size_t)(B + 1) * 4);
  int*   csums  = (int*)alloc((size_t)NCHUNK * 4);
  float* pooled = (float*)alloc((size_t)B * HID * 4);
  float* aggx   = (float*)alloc((size_t)N * IND * 4);
  float* hbuf   = (float*)alloc((size_t)N * HID * 4);
  float* aggh   = (float*)alloc((size_t)N * HID * 4);

  // ---- CSR + norm + segment starts ----
  k_init<<<(N + 255) / 256, 256, 0, stream>>>(indeg, pooled);
  k_count<<<E / 256, 256, 0, stream>>>(eidx, indeg);
  k_seg_starts<<<(N + 255) / 256, 256, 0, stream>>>(batch, starts);
  k_scan1<<<NCHUNK, 256, 0, stream>>>(indeg, rowptr, csums);
  k_scan2<<<1, 128, 0, stream>>>(csums);
  k_scan3<<<(N + 255) / 256, 256, 0, stream>>>(indeg, csums, rowptr, dinv);
  k_fill<<<E / 256, 256, 0, stream>>>(eidx, rowptr, indeg, colsrc);

  // ---- layer 1: aggregate x (20-dim), transform+bias+residual, LN+relu ----
  k_gather20<<<(N + 11) / 12, 256, 0, stream>>>(x, dinv, rowptr, colsrc, aggx);
  k_conv1<<<N / 16, 128, 0, stream>>>(aggx, x, W1, b1, resW, resb, aggh);
  k_lnrelu<<<N / 4, 256, 0, stream>>>(aggh, g1, bb1, hbuf);       // h1

  // ---- layer 2: aggregate h1, GEMM(+b2+residual h1) in-place, LN+relu ----
  k_gather128<<<N / 4, 256, 0, stream>>>(hbuf, dinv, rowptr, colsrc, aggh);
  k_gemm128<<<N / 32, 256, 0, stream>>>(aggh, W2, b2, hbuf, aggh);
  k_lnrelu<<<N / 4, 256, 0, stream>>>(aggh, g2, bb2, hbuf);       // h2

  // ---- layer 3: aggregate h2 (128-dim), pool, then tiny GEMM to 256 ----
  k_gather128<<<N / 4, 256, 0, stream>>>(hbuf, dinv, rowptr, colsrc, aggh);
  k_pool<<<B * 8, 128, 0, stream>>>(aggh, starts, pooled);
  k_final<<<B, 256, 0, stream>>>(pooled, starts, W3, b3, out);
}

// Round 3
// 741.404 us; speedup vs baseline: 1.8576x; 1.1476x over previous
//
#include <hip/hip_runtime.h>
#include <hip/hip_bf16.h>

// GCN: N=100000 nodes, E=1600000 edges, B=64 graphs, 20 -> 128 -> 128 -> 256.
// Strategy:
//  - gcn_conv(h,W) = (scatter_norm(h)) @ W   (linearity) -> aggregate BEFORE the
//    transform: conv1 gathers in 20-dim, conv3 gathers in 128-dim, and the
//    mean-pool also happens BEFORE the final W3 GEMM (pool commutes with W3).
//  - Build CSR (grouped by dst) per launch: count -> scan -> fill. Gathers are
//    then atomic-free.
//  - R1: segment starts via sorted-batch boundary detection (520us atomicMin fix).
//  - R2: 128-dim gather reads bf16 rows pre-scaled by dinv[src] (written by
//    fused LN kernel): row add only in the loop, x2 edges per iteration
//    (half-wave per edge), final cross-half shuffle + one scale by dinv[dst].
//    Residual path stays fp32.

typedef unsigned short ushort_t;
typedef unsigned int uint_t;

constexpr int N  = 100000;
constexpr int E  = 1600000;
constexpr int B  = 64;
constexpr int IND = 20;
constexpr int HID = 128;
constexpr int OUTD = 256;
constexpr int NCHUNK = (N + 1023) / 1024;   // 98 scan chunks

// bf16 helpers (RNE pack, shift-unpack)
__device__ inline ushort_t f2bf(float f) {
  union { float f; uint_t u; } v; v.f = f;
  uint_t r = v.u + 0x7fffu + ((v.u >> 16) & 1u);
  return (ushort_t)(r >> 16);
}
__device__ inline float bflo(uint_t u) { return __uint_as_float(u << 16); }
__device__ inline float bfhi(uint_t u) { return __uint_as_float(u & 0xffff0000u); }

// ---------------- CSR build ----------------

__global__ __launch_bounds__(256) void k_init(int* __restrict__ indeg,
                                              float* __restrict__ pooled) {
  int i = blockIdx.x * 256 + threadIdx.x;
  if (i < N) indeg[i] = 0;
  if (i < B * HID) pooled[i] = 0.f;
}

__global__ __launch_bounds__(256) void k_count(const int* __restrict__ eidx,
                                               int* __restrict__ indeg) {
  int e = blockIdx.x * 256 + threadIdx.x;           // grid exactly E/256
  atomicAdd(&indeg[eidx[E + e]], 1);
}

// batch is sorted: boundary threads plain-store segment starts. No atomics.
__global__ __launch_bounds__(256) void k_seg_starts(const int* __restrict__ batch,
                                                    int* __restrict__ starts) {
  int i = blockIdx.x * 256 + threadIdx.x;
  if (i >= N) return;
  int b = batch[i];
  int prev = (i == 0) ? -1 : batch[i - 1];
  for (int g = prev + 1; g <= b; ++g) starts[g] = i;  // fires only at boundaries
  if (i == N - 1)
    for (int g = b + 1; g <= B; ++g) starts[g] = N;
}

__global__ __launch_bounds__(256) void k_scan1(const int* __restrict__ indeg,
                                               int* __restrict__ rowptr,
                                               int* __restrict__ csums) {
  __shared__ int s[256];
  int tid = threadIdx.x;
  long base = (long)blockIdx.x * 1024 + (long)tid * 4;
  int v0 = (base + 0 < N) ? indeg[base + 0] : 0;
  int v1 = (base + 1 < N) ? indeg[base + 1] : 0;
  int v2 = (base + 2 < N) ? indeg[base + 2] : 0;
  int v3 = (base + 3 < N) ? indeg[base + 3] : 0;
  int p0 = v0, p1 = p0 + v1, p2 = p1 + v2, p3 = p2 + v3;
  s[tid] = p3;
  for (int off = 1; off < 256; off <<= 1) {
    __syncthreads();
    int x = (tid >= off) ? s[tid - off] : 0;
    __syncthreads();
    s[tid] += x;
  }
  int excl = s[tid] - p3;
  if (base + 0 < N) rowptr[base + 1] = excl + p0;
  if (base + 1 < N) rowptr[base + 2] = excl + p1;
  if (base + 2 < N) rowptr[base + 3] = excl + p2;
  if (base + 3 < N) rowptr[base + 4] = excl + p3;
  if (tid == 255) csums[blockIdx.x] = s[255];
}

__global__ __launch_bounds__(128) void k_scan2(int* __restrict__ csums) {
  __shared__ int s[128];
  int tid = threadIdx.x;
  int v = (tid < NCHUNK) ? csums[tid] : 0;
  s[tid] = v;
  for (int off = 1; off < 128; off <<= 1) {
    __syncthreads();
    int x = (tid >= off) ? s[tid - off] : 0;
    __syncthreads();
    s[tid] += x;
  }
  __syncthreads();
  if (tid < NCHUNK) csums[tid] = s[tid] - v;   // exclusive
}

__global__ __launch_bounds__(256) void k_scan3(const int* __restrict__ indeg,
                                               const int* __restrict__ csums,
                                               int* __restrict__ rowptr,
                                               float* __restrict__ dinv) {
  int i = blockIdx.x * 256 + threadIdx.x;
  if (i >= N) return;
  rowptr[i + 1] += csums[i >> 10];
  if (i == 0) rowptr[0] = 0;
  dinv[i] = rsqrtf((float)(1 + indeg[i]));     // deg includes self-loop
}

__global__ __launch_bounds__(256) void k_fill(const int* __restrict__ eidx,
                                              const int* __restrict__ rowptr,
                                              int* __restrict__ indeg,
                                              int* __restrict__ colsrc) {
  int e = blockIdx.x * 256 + threadIdx.x;           // grid exactly E/256
  int s = eidx[e];
  int d = eidx[E + e];
  int old = atomicSub(&indeg[d], 1);
  colsrc[rowptr[d] + old - 1] = s;
}

// ---------------- aggregation (atomic-free gathers) ----------------

// 20-dim gather of raw x: aggx[i] = x[i]*dinv^2 + sum_e x[src]*dinv[s]*dinv[i]
__global__ __launch_bounds__(256) void k_gather20(const float* __restrict__ x,
                                                  const float* __restrict__ dinv,
                                                  const int* __restrict__ rowptr,
                                                  const int* __restrict__ colsrc,
                                                  float* __restrict__ aggx) {
  int t = threadIdx.x;
  if (t >= 240) return;
  int n = t / IND, c = t % IND;
  long i = (long)blockIdx.x * 12 + n;
  if (i >= N) return;
  float di = dinv[i];
  float acc = x[i * IND + c] * di * di;
  int e0 = rowptr[i], e1 = rowptr[i + 1];
  for (int e = e0; e < e1; ++e) {
    int s = colsrc[e];
    acc += x[(long)s * IND + c] * dinv[s] * di;
  }
  aggx[i * IND + c] = acc;
}

// 128-dim gather over bf16 rows pre-scaled by dinv[src].
// One wave per node; lanes 0-31 take edge e, lanes 32-63 edge e+1;
// each lane loads 4 bf16 (8B). agg[i] = dinv[i] * (row(i) + sum_e row(src_e)).
__global__ __launch_bounds__(256) void k_gather128b(const ushort_t* __restrict__ h16,
                                                    const float* __restrict__ dinv,
                                                    const int* __restrict__ rowptr,
                                                    const int* __restrict__ colsrc,
                                                    float* __restrict__ agg) {
  const int lane = threadIdx.x & 63;
  const int half = lane >> 5;
  const int l32 = lane & 31;
  const long i = (long)blockIdx.x * 4 + (threadIdx.x >> 6);   // grid = N/4 exact
  const float di = dinv[i];
  const int c = l32 * 4;
  float a0, a1, a2, a3;
  {
    // self term (h16 row already carries dinv[i]) into half 0 only
    uint2 u = *(const uint2*)(h16 + i * HID + c);
    a0 = half ? 0.f : bflo(u.x);
    a1 = half ? 0.f : bfhi(u.x);
    a2 = half ? 0.f : bflo(u.y);
    a3 = half ? 0.f : bfhi(u.y);
  }
  const int e0 = rowptr[i], e1 = rowptr[i + 1];
#pragma unroll 2
  for (int e = e0; e < e1; e += 2) {
    int idx = e + half;
    bool valid = idx < e1;
    int s = colsrc[valid ? idx : e];
    uint2 u = *(const uint2*)(h16 + (long)s * HID + c);
    if (valid) {
      a0 += bflo(u.x); a1 += bfhi(u.x);
      a2 += bflo(u.y); a3 += bfhi(u.y);
    }
  }
  a0 += __shfl_xor(a0, 32);
  a1 += __shfl_xor(a1, 32);
  a2 += __shfl_xor(a2, 32);
  a3 += __shfl_xor(a3, 32);
  if (half == 0)
    *(float4*)&agg[i * HID + c] = make_float4(a0 * di, a1 * di, a2 * di, a3 * di);
}

// ---------------- dense layers ----------------

// T = aggx@W1 + b1 + x@res_W + res_b   (pre-LN1 sum), 16 nodes / block
__global__ __launch_bounds__(128) void k_conv1(const float* __restrict__ aggx,
                                               const float* __restrict__ x,
                                               const float* __restrict__ W1,
                                               const float* __restrict__ b1,
                                               const float* __restrict__ Wr,
                                               const float* __restrict__ rb,
                                               float* __restrict__ T) {
  __shared__ float W1s[IND * HID], Wrs[IND * HID], as[16 * IND], xs[16 * IND];
  int tid = threadIdx.x;
  for (int i = tid; i < IND * HID; i += 128) { W1s[i] = W1[i]; Wrs[i] = Wr[i]; }
  long node0 = (long)blockIdx.x * 16;                 // grid = N/16 exact
  for (int i = tid; i < 16 * IND; i += 128) {
    as[i] = aggx[node0 * IND + i];
    xs[i] = x[node0 * IND + i];
  }
  float bj = b1[tid] + rb[tid];
  __syncthreads();
  for (int n = 0; n < 16; ++n) {
    float a = bj;
#pragma unroll
    for (int k = 0; k < IND; ++k) {
      a = fmaf(as[n * IND + k], W1s[k * HID + tid], a);
      a = fmaf(xs[n * IND + k], Wrs[k * HID + tid], a);
    }
    T[(node0 + n) * HID + tid] = a;
  }
}

// out = in@W + bias + res   (128x128, K-tiled in LDS, 32 nodes / block, in-place safe)
__global__ __launch_bounds__(256) void k_gemm128(const float* in,
                                                 const float* __restrict__ W,
                                                 const float* __restrict__ bias,
                                                 const float* __restrict__ res,
                                                 float* out) {
  constexpr int NPB = 32;
  __shared__ float Wt[32 * HID];
  __shared__ float Xs[NPB * HID];
  const int tid = threadIdx.x;
  const long node0 = (long)blockIdx.x * NPB;          // grid = N/32 exact
  {
    const float4* sp = (const float4*)(in + node0 * HID);
    float4* dp = (float4*)Xs;
    for (int i = tid; i < NPB * HID / 4; i += 256) dp[i] = sp[i];
  }
  const int nidx = tid >> 5;          // 8 nodes in flight
  const int col = (tid & 31) * 4;     // 32 threads cover 128 cols
  float4 acc[4];
#pragma unroll
  for (int m = 0; m < 4; ++m) acc[m] = make_float4(0.f, 0.f, 0.f, 0.f);
  for (int kt = 0; kt < 4; ++kt) {
    __syncthreads();
    {
      const float4* wp = (const float4*)(W + kt * 32 * HID);
      float4* wd = (float4*)Wt;
      for (int i = tid; i < 32 * HID / 4; i += 256) wd[i] = wp[i];
    }
    __syncthreads();
#pragma unroll
    for (int k = 0; k < 32; k += 4) {
      float4 w[4];
#pragma unroll
      for (int kk = 0; kk < 4; ++kk) w[kk] = *(const float4*)&Wt[(k + kk) * HID + col];
#pragma unroll
      for (int m = 0; m < 4; ++m) {
        const int nm = nidx + m * 8;
        float4 x4 = *(const float4*)&Xs[nm * HID + kt * 32 + k];
        float xv[4] = {x4.x, x4.y, x4.z, x4.w};
#pragma unroll
        for (int kk = 0; kk < 4; ++kk) {
          acc[m].x = fmaf(xv[kk], w[kk].x, acc[m].x);
          acc[m].y = fmaf(xv[kk], w[kk].y, acc[m].y);
          acc[m].z = fmaf(xv[kk], w[kk].z, acc[m].z);
          acc[m].w = fmaf(xv[kk], w[kk].w, acc[m].w);
        }
      }
    }
  }
  float4 bz = *(const float4*)&bias[col];
#pragma unroll
  for (int m = 0; m < 4; ++m) {
    long nm = node0 + nidx + m * 8;
    float4 rz = *(const float4*)&res[nm * HID + col];
    float4 o = acc[m];
    o.x += bz.x + rz.x; o.y += bz.y + rz.y;
    o.z += bz.z + rz.z; o.w += bz.w + rz.w;
    *(float4*)&out[nm * HID + col] = o;
  }
}

// relu(layernorm(in)): optional fp32 out (residual path) + bf16 out scaled by
// dinv[i] (gather payload). One wave per node.
__global__ __launch_bounds__(256) void k_lnrelu(const float* __restrict__ in,
                                                const float* __restrict__ g,
                                                const float* __restrict__ b,
                                                const float* __restrict__ dinv,
                                                float* __restrict__ outf,
                                                ushort_t* __restrict__ out16) {
  const int lane = threadIdx.x & 63;
  const long i = (long)blockIdx.x * 4 + (threadIdx.x >> 6);   // grid = N/4 exact
  const int c = lane * 2;
  float2 v = *(const float2*)&in[i * HID + c];
  float s = v.x + v.y, q = v.x * v.x + v.y * v.y;
#pragma unroll
  for (int off = 32; off; off >>= 1) {
    s += __shfl_xor(s, off);
    q += __shfl_xor(q, off);
  }
  const float mu = s * (1.f / 128.f);
  const float var = q * (1.f / 128.f) - mu * mu;
  const float rs = rsqrtf(var + 1e-5f);
  float2 gg = *(const float2*)&g[c], bb = *(const float2*)&b[c];
  float y0 = fmaxf(fmaf((v.x - mu) * rs, gg.x, bb.x), 0.f);
  float y1 = fmaxf(fmaf((v.y - mu) * rs, gg.y, bb.y), 0.f);
  if (outf) *(float2*)&outf[i * HID + c] = make_float2(y0, y1);
  const float di = dinv[i];
  ushort_t p0 = f2bf(y0 * di), p1 = f2bf(y1 * di);
  *(uint_t*)&out16[i * HID + c] = (uint_t)p0 | ((uint_t)p1 << 16);
}

// ---------------- pooling + final GEMM ----------------

__global__ __launch_bounds__(128) void k_pool(const float* __restrict__ agg,
                                              const int* __restrict__ starts,
                                              float* __restrict__ pooled) {
  int g = blockIdx.x >> 3, part = blockIdx.x & 7;
  int s0 = starts[g], s1 = starts[g + 1];
  int len = s1 - s0;
  int chunk = (len + 7) >> 3;
  int a = s0 + part * chunk;
  int bnd = min(a + chunk, s1);
  if (a >= bnd) return;
  float acc = 0.f;
  for (long i = a; i < bnd; ++i) acc += agg[i * HID + threadIdx.x];
  atomicAdd(&pooled[g * HID + threadIdx.x], acc);
}

// out[g] = (pooled[g]/cnt) @ W3 + b3
__global__ __launch_bounds__(256) void k_final(const float* __restrict__ pooled,
                                               const int* __restrict__ starts,
                                               const float* __restrict__ W3,
                                               const float* __restrict__ b3,
                                               float* __restrict__ out) {
  __shared__ float p[HID];
  int g = blockIdx.x, tid = threadIdx.x;
  int len = starts[g + 1] - starts[g];
  float scale = 1.0f / fmaxf((float)len, 1.0f);
  if (tid < HID) p[tid] = pooled[g * HID + tid] * scale;
  __syncthreads();
  float a = b3[tid];
  for (int k = 0; k < HID; ++k) a = fmaf(p[k], W3[k * OUTD + tid], a);
  out[g * OUTD + tid] = a;
}

// ---------------- launch ----------------

extern "C" void kernel_launch(void* const* d_in, const int* in_sizes, int n_in,
                              void* d_out, int out_size, void* d_ws, size_t ws_size,
                              hipStream_t stream) {
  const float* x    = (const float*)d_in[0];
  const int*   eidx = (const int*)d_in[1];
  const int*   batch= (const int*)d_in[2];
  const float* W1   = (const float*)d_in[3];
  const float* b1   = (const float*)d_in[4];
  const float* W2   = (const float*)d_in[5];
  const float* b2   = (const float*)d_in[6];
  const float* W3   = (const float*)d_in[7];
  const float* b3   = (const float*)d_in[8];
  const float* resW = (const float*)d_in[9];
  const float* resb = (const float*)d_in[10];
  const float* g1   = (const float*)d_in[11];
  const float* bb1  = (const float*)d_in[12];
  const float* g2   = (const float*)d_in[13];
  const float* bb2  = (const float*)d_in[14];
  float* out = (float*)d_out;

  char* w = (char*)d_ws;
  size_t off = 0;
  auto alloc = [&](size_t bytes) {
    char* p = w + off;
    off = (off + bytes + 1023) & ~(size_t)1023;
    return p;
  };
  float* dinv   = (float*)alloc((size_t)N * 4);
  int*   indeg  = (int*)alloc((size_t)N * 4);
  int*   rowptr = (int*)alloc((size_t)(N + 1) * 4);
  int*   colsrc = (int*)alloc((size_t)E * 4);
  int*   starts = (int*)alloc((size_t)(B + 1) * 4);
  int*   csums  = (int*)alloc((size_t)NCHUNK * 4);
  float* pooled = (float*)alloc((size_t)B * HID * 4);
  float* aggx   = (float*)alloc((size_t)N * IND * 4);
  float* hbuf   = (float*)alloc((size_t)N * HID * 4);
  float* aggh   = (float*)alloc((size_t)N * HID * 4);
  ushort_t* h16 = (ushort_t*)alloc((size_t)N * HID * 2);

  // ---- CSR + norm + segment starts ----
  k_init<<<(N + 255) / 256, 256, 0, stream>>>(indeg, pooled);
  k_count<<<E / 256, 256, 0, stream>>>(eidx, indeg);
  k_seg_starts<<<(N + 255) / 256, 256, 0, stream>>>(batch, starts);
  k_scan1<<<NCHUNK, 256, 0, stream>>>(indeg, rowptr, csums);
  k_scan2<<<1, 128, 0, stream>>>(csums);
  k_scan3<<<(N + 255) / 256, 256, 0, stream>>>(indeg, csums, rowptr, dinv);
  k_fill<<<E / 256, 256, 0, stream>>>(eidx, rowptr, indeg, colsrc);

  // ---- layer 1: aggregate x (20-dim), transform+bias+residual, LN+relu ----
  k_gather20<<<(N + 11) / 12, 256, 0, stream>>>(x, dinv, rowptr, colsrc, aggx);
  k_conv1<<<N / 16, 128, 0, stream>>>(aggx, x, W1, b1, resW, resb, aggh);
  k_lnrelu<<<N / 4, 256, 0, stream>>>(aggh, g1, bb1, dinv, hbuf, h16);  // h1 fp32+bf16

  // ---- layer 2: aggregate h1 (bf16), GEMM(+b2+residual h1) in-place, LN+relu ----
  k_gather128b<<<N / 4, 256, 0, stream>>>(h16, dinv, rowptr, colsrc, aggh);
  k_gemm128<<<N / 32, 256, 0, stream>>>(aggh, W2, b2, hbuf, aggh);
  k_lnrelu<<<N / 4, 256, 0, stream>>>(aggh, g2, bb2, dinv, nullptr, h16); // h2 bf16 only

  // ---- layer 3: aggregate h2 (128-dim), pool, then tiny GEMM to 256 ----
  k_gather128b<<<N / 4, 256, 0, stream>>>(h16, dinv, rowptr, colsrc, aggh);
  k_pool<<<B * 8, 128, 0, stream>>>(aggh, starts, pooled);
  k_final<<<B, 256, 0, stream>>>(pooled, starts, W3, b3, out);
}

// Round 4
// 607.197 us; speedup vs baseline: 2.2681x; 1.2210x over previous
//
#include <hip/hip_runtime.h>
#include <hip/hip_bf16.h>

// GCN: N=100000 nodes, E=1600000 edges, B=64 graphs, 20 -> 128 -> 128 -> 256.
// Strategy:
//  - gcn_conv(h,W) = (scatter_norm(h)) @ W   (linearity) -> aggregate BEFORE the
//    transform: conv1 gathers in 20-dim, conv3 gathers in 128-dim, and the
//    mean-pool also happens BEFORE the final W3 GEMM (pool commutes with W3).
//  - R1: segment starts via sorted-batch boundary detection (520us atomicMin fix).
//  - R2: 128-dim gather reads bf16 rows pre-scaled by dinv[src]; 2 edges/wave-iter.
//  - R3: CSR build rewritten as two-level bucket sort (hist -> scan -> scatter ->
//    per-bucket LDS counting sort). R2's k_fill did 1.6M random 4B scatters over
//    6.4MB -> 107MB HBM writes (17x amp); now all HBM writes are coalesced runs
//    and the random scatter happens in LDS. Also kills k_count's random atomics
//    and the 3 scan kernels (rowptr/dinv fall out of the bucket pass).

typedef unsigned short ushort_t;
typedef unsigned int uint_t;

constexpr int N  = 100000;
constexpr int E  = 1600000;
constexpr int B  = 64;
constexpr int IND = 20;
constexpr int HID = 128;
constexpr int OUTD = 256;

constexpr int NBUK = (N + 127) / 128;   // 782 buckets of 128 nodes
constexpr int GB   = 256;               // hist/scatter blocks
constexpr int EPB  = E / GB;            // 6250 edges per block
constexpr int BMAX = 3072;              // LDS cap per bucket (mean 2048, sd ~45)

// bf16 helpers (RNE pack, shift-unpack)
__device__ inline ushort_t f2bf(float f) {
  union { float f; uint_t u; } v; v.f = f;
  uint_t r = v.u + 0x7fffu + ((v.u >> 16) & 1u);
  return (ushort_t)(r >> 16);
}
__device__ inline float bflo(uint_t u) { return __uint_as_float(u << 16); }
__device__ inline float bfhi(uint_t u) { return __uint_as_float(u & 0xffff0000u); }

// ---------------- misc init ----------------

__global__ __launch_bounds__(256) void k_init(float* __restrict__ pooled) {
  int i = blockIdx.x * 256 + threadIdx.x;
  if (i < B * HID) pooled[i] = 0.f;
}

// batch is sorted: boundary threads plain-store segment starts. No atomics.
__global__ __launch_bounds__(256) void k_seg_starts(const int* __restrict__ batch,
                                                    int* __restrict__ starts) {
  int i = blockIdx.x * 256 + threadIdx.x;
  if (i >= N) return;
  int b = batch[i];
  int prev = (i == 0) ? -1 : batch[i - 1];
  for (int g = prev + 1; g <= b; ++g) starts[g] = i;  // fires only at boundaries
  if (i == N - 1)
    for (int g = b + 1; g <= B; ++g) starts[g] = N;
}

// ---------------- CSR build: two-level bucket sort ----------------

// Pass A: per-block histogram over dst>>7 (LDS-privatized, coalesced write).
__global__ __launch_bounds__(256) void k_hist(const int* __restrict__ eidx,
                                              int* __restrict__ hist) {
  __shared__ int h[NBUK];
  for (int i = threadIdx.x; i < NBUK; i += 256) h[i] = 0;
  __syncthreads();
  const long base = (long)blockIdx.x * EPB;
  for (int i = threadIdx.x; i < EPB; i += 256)
    atomicAdd(&h[eidx[E + base + i] >> 7], 1);
  __syncthreads();
  for (int i = threadIdx.x; i < NBUK; i += 256)
    hist[(long)blockIdx.x * NBUK + i] = h[i];
}

// Pass B: for each bucket, exclusive scan across the 256 block counts.
__global__ __launch_bounds__(256) void k_bscan(int* __restrict__ hist,
                                               int* __restrict__ btotal) {
  __shared__ int s[256];
  const int j = blockIdx.x, tid = threadIdx.x;
  int v = hist[(long)tid * NBUK + j];
  s[tid] = v;
  for (int off = 1; off < 256; off <<= 1) {
    __syncthreads();
    int x = (tid >= off) ? s[tid - off] : 0;
    __syncthreads();
    s[tid] += x;
  }
  hist[(long)tid * NBUK + j] = s[tid] - v;   // exclusive within bucket
  if (tid == 255) btotal[j] = s[255];
}

// Exclusive scan over the 782 bucket totals -> bexcl[0..NBUK], plus rowptr[N]=E.
__global__ __launch_bounds__(256) void k_bktscan(const int* __restrict__ btotal,
                                                 int* __restrict__ bexcl,
                                                 int* __restrict__ rowptr) {
  __shared__ int s[256];
  int tid = threadIdx.x;
  int base = tid * 4;
  int v0 = (base + 0 < NBUK) ? btotal[base + 0] : 0;
  int v1 = (base + 1 < NBUK) ? btotal[base + 1] : 0;
  int v2 = (base + 2 < NBUK) ? btotal[base + 2] : 0;
  int v3 = (base + 3 < NBUK) ? btotal[base + 3] : 0;
  int p0 = v0, p1 = p0 + v1, p2 = p1 + v2, p3 = p2 + v3;
  s[tid] = p3;
  for (int off = 1; off < 256; off <<= 1) {
    __syncthreads();
    int x = (tid >= off) ? s[tid - off] : 0;
    __syncthreads();
    s[tid] += x;
  }
  int excl = s[tid] - p3;
  if (base + 0 < NBUK) bexcl[base + 1] = excl + p0;
  if (base + 1 < NBUK) bexcl[base + 2] = excl + p1;
  if (base + 2 < NBUK) bexcl[base + 3] = excl + p2;
  if (base + 3 < NBUK) bexcl[base + 4] = excl + p3;
  if (tid == 0) { bexcl[0] = 0; rowptr[N] = E; }
}

// Pass D: scatter packed (src | dstlow<<20) into bucket-ordered ebuf.
// Same-block-same-bucket edges land consecutively -> short coalesced runs.
__global__ __launch_bounds__(256) void k_scatter(const int* __restrict__ eidx,
                                                 const int* __restrict__ hist,
                                                 const int* __restrict__ bexcl,
                                                 int* __restrict__ ebuf) {
  __shared__ int h[NBUK];
  for (int i = threadIdx.x; i < NBUK; i += 256)
    h[i] = bexcl[i] + hist[(long)blockIdx.x * NBUK + i];
  __syncthreads();
  const long base = (long)blockIdx.x * EPB;
  for (int i = threadIdx.x; i < EPB; i += 256) {
    int srcv = eidx[base + i];
    int d = eidx[E + base + i];
    int pos = atomicAdd(&h[d >> 7], 1);
    ebuf[pos] = srcv | ((d & 127) << 20);
  }
}

// Pass C: one block per bucket. LDS histogram over 128 local nodes -> degrees,
// rowptr, dinv; LDS counting-sort scatter; coalesced colsrc stream-out.
__global__ __launch_bounds__(256) void k_csr(const int* __restrict__ ebuf,
                                             const int* __restrict__ bexcl,
                                             int* __restrict__ rowptr,
                                             float* __restrict__ dinv,
                                             int* __restrict__ colsrc) {
  __shared__ int deg[128], s[128], cur[128];
  __shared__ int lout[BMAX];
  const int j = blockIdx.x, tid = threadIdx.x;
  const int e0 = bexcl[j], e1 = bexcl[j + 1];
  const int cnt = e1 - e0;
  if (tid < 128) deg[tid] = 0;
  __syncthreads();
  for (int i = tid; i < cnt; i += 256)
    atomicAdd(&deg[(ebuf[e0 + i] >> 20) & 127], 1);
  __syncthreads();
  int v = (tid < 128) ? deg[tid] : 0;
  if (tid < 128) s[tid] = v;
  for (int off = 1; off < 128; off <<= 1) {
    __syncthreads();
    int x = (tid < 128 && tid >= off) ? s[tid - off] : 0;
    __syncthreads();
    if (tid < 128) s[tid] += x;
  }
  __syncthreads();
  if (tid < 128) {
    int ex = s[tid] - v;
    cur[tid] = ex;
    int node = j * 128 + tid;
    if (node < N) {
      rowptr[node] = e0 + ex;
      dinv[node] = rsqrtf((float)(1 + v));   // deg includes self-loop
    }
  }
  __syncthreads();
  if (cnt <= BMAX) {
    for (int i = tid; i < cnt; i += 256) {
      int p = ebuf[e0 + i];
      int pos = atomicAdd(&cur[(p >> 20) & 127], 1);
      lout[pos] = p & 0xFFFFF;
    }
    __syncthreads();
    for (int i = tid; i < cnt; i += 256) colsrc[e0 + i] = lout[i];
  } else {  // safety fallback: direct global scatter (window still tiny -> L2)
    for (int i = tid; i < cnt; i += 256) {
      int p = ebuf[e0 + i];
      int pos = atomicAdd(&cur[(p >> 20) & 127], 1);
      colsrc[e0 + pos] = p & 0xFFFFF;
    }
  }
}

// ---------------- aggregation (atomic-free gathers) ----------------

// 20-dim gather of raw x: aggx[i] = x[i]*dinv^2 + sum_e x[src]*dinv[s]*dinv[i]
__global__ __launch_bounds__(256) void k_gather20(const float* __restrict__ x,
                                                  const float* __restrict__ dinv,
                                                  const int* __restrict__ rowptr,
                                                  const int* __restrict__ colsrc,
                                                  float* __restrict__ aggx) {
  int t = threadIdx.x;
  if (t >= 240) return;
  int n = t / IND, c = t % IND;
  long i = (long)blockIdx.x * 12 + n;
  if (i >= N) return;
  float di = dinv[i];
  float acc = x[i * IND + c] * di * di;
  int e0 = rowptr[i], e1 = rowptr[i + 1];
  for (int e = e0; e < e1; ++e) {
    int s = colsrc[e];
    acc += x[(long)s * IND + c] * dinv[s] * di;
  }
  aggx[i * IND + c] = acc;
}

// 128-dim gather over bf16 rows pre-scaled by dinv[src].
// One wave per node; lanes 0-31 take edge e, lanes 32-63 edge e+1;
// each lane loads 4 bf16 (8B). agg[i] = dinv[i] * (row(i) + sum_e row(src_e)).
__global__ __launch_bounds__(256) void k_gather128b(const ushort_t* __restrict__ h16,
                                                    const float* __restrict__ dinv,
                                                    const int* __restrict__ rowptr,
                                                    const int* __restrict__ colsrc,
                                                    float* __restrict__ agg) {
  const int lane = threadIdx.x & 63;
  const int half = lane >> 5;
  const int l32 = lane & 31;
  const long i = (long)blockIdx.x * 4 + (threadIdx.x >> 6);   // grid = N/4 exact
  const float di = dinv[i];
  const int c = l32 * 4;
  float a0, a1, a2, a3;
  {
    // self term (h16 row already carries dinv[i]) into half 0 only
    uint2 u = *(const uint2*)(h16 + i * HID + c);
    a0 = half ? 0.f : bflo(u.x);
    a1 = half ? 0.f : bfhi(u.x);
    a2 = half ? 0.f : bflo(u.y);
    a3 = half ? 0.f : bfhi(u.y);
  }
  const int e0 = rowptr[i], e1 = rowptr[i + 1];
#pragma unroll 2
  for (int e = e0; e < e1; e += 2) {
    int idx = e + half;
    bool valid = idx < e1;
    int s = colsrc[valid ? idx : e];
    uint2 u = *(const uint2*)(h16 + (long)s * HID + c);
    if (valid) {
      a0 += bflo(u.x); a1 += bfhi(u.x);
      a2 += bflo(u.y); a3 += bfhi(u.y);
    }
  }
  a0 += __shfl_xor(a0, 32);
  a1 += __shfl_xor(a1, 32);
  a2 += __shfl_xor(a2, 32);
  a3 += __shfl_xor(a3, 32);
  if (half == 0)
    *(float4*)&agg[i * HID + c] = make_float4(a0 * di, a1 * di, a2 * di, a3 * di);
}

// ---------------- dense layers ----------------

// T = aggx@W1 + b1 + x@res_W + res_b   (pre-LN1 sum), 16 nodes / block
__global__ __launch_bounds__(128) void k_conv1(const float* __restrict__ aggx,
                                               const float* __restrict__ x,
                                               const float* __restrict__ W1,
                                               const float* __restrict__ b1,
                                               const float* __restrict__ Wr,
                                               const float* __restrict__ rb,
                                               float* __restrict__ T) {
  __shared__ float W1s[IND * HID], Wrs[IND * HID], as[16 * IND], xs[16 * IND];
  int tid = threadIdx.x;
  for (int i = tid; i < IND * HID; i += 128) { W1s[i] = W1[i]; Wrs[i] = Wr[i]; }
  long node0 = (long)blockIdx.x * 16;                 // grid = N/16 exact
  for (int i = tid; i < 16 * IND; i += 128) {
    as[i] = aggx[node0 * IND + i];
    xs[i] = x[node0 * IND + i];
  }
  float bj = b1[tid] + rb[tid];
  __syncthreads();
  for (int n = 0; n < 16; ++n) {
    float a = bj;
#pragma unroll
    for (int k = 0; k < IND; ++k) {
      a = fmaf(as[n * IND + k], W1s[k * HID + tid], a);
      a = fmaf(xs[n * IND + k], Wrs[k * HID + tid], a);
    }
    T[(node0 + n) * HID + tid] = a;
  }
}

// out = in@W + bias + res   (128x128, K-tiled in LDS, 32 nodes / block, in-place safe)
__global__ __launch_bounds__(256) void k_gemm128(const float* in,
                                                 const float* __restrict__ W,
                                                 const float* __restrict__ bias,
                                                 const float* __restrict__ res,
                                                 float* out) {
  constexpr int NPB = 32;
  __shared__ float Wt[32 * HID];
  __shared__ float Xs[NPB * HID];
  const int tid = threadIdx.x;
  const long node0 = (long)blockIdx.x * NPB;          // grid = N/32 exact
  {
    const float4* sp = (const float4*)(in + node0 * HID);
    float4* dp = (float4*)Xs;
    for (int i = tid; i < NPB * HID / 4; i += 256) dp[i] = sp[i];
  }
  const int nidx = tid >> 5;          // 8 nodes in flight
  const int col = (tid & 31) * 4;     // 32 threads cover 128 cols
  float4 acc[4];
#pragma unroll
  for (int m = 0; m < 4; ++m) acc[m] = make_float4(0.f, 0.f, 0.f, 0.f);
  for (int kt = 0; kt < 4; ++kt) {
    __syncthreads();
    {
      const float4* wp = (const float4*)(W + kt * 32 * HID);
      float4* wd = (float4*)Wt;
      for (int i = tid; i < 32 * HID / 4; i += 256) wd[i] = wp[i];
    }
    __syncthreads();
#pragma unroll
    for (int k = 0; k < 32; k += 4) {
      float4 w[4];
#pragma unroll
      for (int kk = 0; kk < 4; ++kk) w[kk] = *(const float4*)&Wt[(k + kk) * HID + col];
#pragma unroll
      for (int m = 0; m < 4; ++m) {
        const int nm = nidx + m * 8;
        float4 x4 = *(const float4*)&Xs[nm * HID + kt * 32 + k];
        float xv[4] = {x4.x, x4.y, x4.z, x4.w};
#pragma unroll
        for (int kk = 0; kk < 4; ++kk) {
          acc[m].x = fmaf(xv[kk], w[kk].x, acc[m].x);
          acc[m].y = fmaf(xv[kk], w[kk].y, acc[m].y);
          acc[m].z = fmaf(xv[kk], w[kk].z, acc[m].z);
          acc[m].w = fmaf(xv[kk], w[kk].w, acc[m].w);
        }
      }
    }
  }
  float4 bz = *(const float4*)&bias[col];
#pragma unroll
  for (int m = 0; m < 4; ++m) {
    long nm = node0 + nidx + m * 8;
    float4 rz = *(const float4*)&res[nm * HID + col];
    float4 o = acc[m];
    o.x += bz.x + rz.x; o.y += bz.y + rz.y;
    o.z += bz.z + rz.z; o.w += bz.w + rz.w;
    *(float4*)&out[nm * HID + col] = o;
  }
}

// relu(layernorm(in)): optional fp32 out (residual path) + bf16 out scaled by
// dinv[i] (gather payload). One wave per node.
__global__ __launch_bounds__(256) void k_lnrelu(const float* __restrict__ in,
                                                const float* __restrict__ g,
                                                const float* __restrict__ b,
                                                const float* __restrict__ dinv,
                                                float* __restrict__ outf,
                                                ushort_t* __restrict__ out16) {
  const int lane = threadIdx.x & 63;
  const long i = (long)blockIdx.x * 4 + (threadIdx.x >> 6);   // grid = N/4 exact
  const int c = lane * 2;
  float2 v = *(const float2*)&in[i * HID + c];
  float s = v.x + v.y, q = v.x * v.x + v.y * v.y;
#pragma unroll
  for (int off = 32; off; off >>= 1) {
    s += __shfl_xor(s, off);
    q += __shfl_xor(q, off);
  }
  const float mu = s * (1.f / 128.f);
  const float var = q * (1.f / 128.f) - mu * mu;
  const float rs = rsqrtf(var + 1e-5f);
  float2 gg = *(const float2*)&g[c], bb = *(const float2*)&b[c];
  float y0 = fmaxf(fmaf((v.x - mu) * rs, gg.x, bb.x), 0.f);
  float y1 = fmaxf(fmaf((v.y - mu) * rs, gg.y, bb.y), 0.f);
  if (outf) *(float2*)&outf[i * HID + c] = make_float2(y0, y1);
  const float di = dinv[i];
  ushort_t p0 = f2bf(y0 * di), p1 = f2bf(y1 * di);
  *(uint_t*)&out16[i * HID + c] = (uint_t)p0 | ((uint_t)p1 << 16);
}

// ---------------- pooling + final GEMM ----------------

__global__ __launch_bounds__(128) void k_pool(const float* __restrict__ agg,
                                              const int* __restrict__ starts,
                                              float* __restrict__ pooled) {
  int g = blockIdx.x >> 3, part = blockIdx.x & 7;
  int s0 = starts[g], s1 = starts[g + 1];
  int len = s1 - s0;
  int chunk = (len + 7) >> 3;
  int a = s0 + part * chunk;
  int bnd = min(a + chunk, s1);
  if (a >= bnd) return;
  float acc = 0.f;
  for (long i = a; i < bnd; ++i) acc += agg[i * HID + threadIdx.x];
  atomicAdd(&pooled[g * HID + threadIdx.x], acc);
}

// out[g] = (pooled[g]/cnt) @ W3 + b3
__global__ __launch_bounds__(256) void k_final(const float* __restrict__ pooled,
                                               const int* __restrict__ starts,
                                               const float* __restrict__ W3,
                                               const float* __restrict__ b3,
                                               float* __restrict__ out) {
  __shared__ float p[HID];
  int g = blockIdx.x, tid = threadIdx.x;
  int len = starts[g + 1] - starts[g];
  float scale = 1.0f / fmaxf((float)len, 1.0f);
  if (tid < HID) p[tid] = pooled[g * HID + tid] * scale;
  __syncthreads();
  float a = b3[tid];
  for (int k = 0; k < HID; ++k) a = fmaf(p[k], W3[k * OUTD + tid], a);
  out[g * OUTD + tid] = a;
}

// ---------------- launch ----------------

extern "C" void kernel_launch(void* const* d_in, const int* in_sizes, int n_in,
                              void* d_out, int out_size, void* d_ws, size_t ws_size,
                              hipStream_t stream) {
  const float* x    = (const float*)d_in[0];
  const int*   eidx = (const int*)d_in[1];
  const int*   batch= (const int*)d_in[2];
  const float* W1   = (const float*)d_in[3];
  const float* b1   = (const float*)d_in[4];
  const float* W2   = (const float*)d_in[5];
  const float* b2   = (const float*)d_in[6];
  const float* W3   = (const float*)d_in[7];
  const float* b3   = (const float*)d_in[8];
  const float* resW = (const float*)d_in[9];
  const float* resb = (const float*)d_in[10];
  const float* g1   = (const float*)d_in[11];
  const float* bb1  = (const float*)d_in[12];
  const float* g2   = (const float*)d_in[13];
  const float* bb2  = (const float*)d_in[14];
  float* out = (float*)d_out;

  char* w = (char*)d_ws;
  size_t off = 0;
  auto alloc = [&](size_t bytes) {
    char* p = w + off;
    off = (off + bytes + 1023) & ~(size_t)1023;
    return p;
  };
  float* dinv   = (float*)alloc((size_t)N * 4);
  int*   rowptr = (int*)alloc((size_t)(N + 1) * 4);
  int*   colsrc = (int*)alloc((size_t)E * 4);
  int*   ebuf   = (int*)alloc((size_t)E * 4);
  int*   hist   = (int*)alloc((size_t)GB * NBUK * 4);
  int*   btotal = (int*)alloc((size_t)NBUK * 4);
  int*   bexcl  = (int*)alloc((size_t)(NBUK + 1) * 4);
  int*   starts = (int*)alloc((size_t)(B + 1) * 4);
  float* pooled = (float*)alloc((size_t)B * HID * 4);
  float* aggx   = (float*)alloc((size_t)N * IND * 4);
  float* hbuf   = (float*)alloc((size_t)N * HID * 4);
  float* aggh   = (float*)alloc((size_t)N * HID * 4);
  ushort_t* h16 = (ushort_t*)alloc((size_t)N * HID * 2);

  // ---- CSR (bucket sort) + norm + segment starts ----
  k_init<<<(B * HID + 255) / 256, 256, 0, stream>>>(pooled);
  k_seg_starts<<<(N + 255) / 256, 256, 0, stream>>>(batch, starts);
  k_hist<<<GB, 256, 0, stream>>>(eidx, hist);
  k_bscan<<<NBUK, 256, 0, stream>>>(hist, btotal);
  k_bktscan<<<1, 256, 0, stream>>>(btotal, bexcl, rowptr);
  k_scatter<<<GB, 256, 0, stream>>>(eidx, hist, bexcl, ebuf);
  k_csr<<<NBUK, 256, 0, stream>>>(ebuf, bexcl, rowptr, dinv, colsrc);

  // ---- layer 1: aggregate x (20-dim), transform+bias+residual, LN+relu ----
  k_gather20<<<(N + 11) / 12, 256, 0, stream>>>(x, dinv, rowptr, colsrc, aggx);
  k_conv1<<<N / 16, 128, 0, stream>>>(aggx, x, W1, b1, resW, resb, aggh);
  k_lnrelu<<<N / 4, 256, 0, stream>>>(aggh, g1, bb1, dinv, hbuf, h16);  // h1 fp32+bf16

  // ---- layer 2: aggregate h1 (bf16), GEMM(+b2+residual h1) in-place, LN+relu ----
  k_gather128b<<<N / 4, 256, 0, stream>>>(h16, dinv, rowptr, colsrc, aggh);
  k_gemm128<<<N / 32, 256, 0, stream>>>(aggh, W2, b2, hbuf, aggh);
  k_lnrelu<<<N / 4, 256, 0, stream>>>(aggh, g2, bb2, dinv, nullptr, h16); // h2 bf16 only

  // ---- layer 3: aggregate h2 (128-dim), pool, then tiny GEMM to 256 ----
  k_gather128b<<<N / 4, 256, 0, stream>>>(h16, dinv, rowptr, colsrc, aggh);
  k_pool<<<B * 8, 128, 0, stream>>>(aggh, starts, pooled);
  k_final<<<B, 256, 0, stream>>>(pooled, starts, W3, b3, out);
}

// Round 5
// 484.053 us; speedup vs baseline: 2.8451x; 1.2544x over previous
//
#include <hip/hip_runtime.h>
#include <hip/hip_bf16.h>

// GCN: N=100000 nodes, E=1600000 edges, B=64 graphs, 20 -> 128 -> 128 -> 256.
// Strategy:
//  - gcn_conv(h,W) = (scatter_norm(h)) @ W   (linearity) -> aggregate BEFORE the
//    transform: conv1 gathers in 20-dim, conv3 gathers in 128-dim, and the
//    mean-pool also happens BEFORE the final W3 GEMM (pool commutes with W3).
//  - R1: segment starts via sorted-batch boundary detection (520us atomicMin fix).
//  - R2: 128-dim gather reads bf16 rows pre-scaled by dinv[src].
//  - R3: CSR build as two-level bucket sort (all random scatters live in LDS).
//  - R4: gathers widened to 16B/lane (uint4, 4 edges/wave-iter, 2-level shuffle
//    reduce); layer-3 gather fuses the mean-pool (no agg write / pool re-read);
//    20-dim gather reads a bf16 x*dinv table (4MB -> L2-resident).

typedef unsigned short ushort_t;
typedef unsigned int uint_t;

constexpr int N  = 100000;
constexpr int E  = 1600000;
constexpr int B  = 64;
constexpr int IND = 20;
constexpr int HID = 128;
constexpr int OUTD = 256;

constexpr int NBUK = (N + 127) / 128;   // 782 buckets of 128 nodes
constexpr int GB   = 256;               // hist/scatter blocks
constexpr int EPB  = E / GB;            // 6250 edges per block
constexpr int BMAX = 3072;              // LDS cap per bucket (mean 2048, sd ~45)

// bf16 helpers (RNE pack, shift-unpack)
__device__ inline ushort_t f2bf(float f) {
  union { float f; uint_t u; } v; v.f = f;
  uint_t r = v.u + 0x7fffu + ((v.u >> 16) & 1u);
  return (ushort_t)(r >> 16);
}
__device__ inline float bflo(uint_t u) { return __uint_as_float(u << 16); }
__device__ inline float bfhi(uint_t u) { return __uint_as_float(u & 0xffff0000u); }

// ---------------- misc init ----------------

__global__ __launch_bounds__(256) void k_init(float* __restrict__ pooled) {
  int i = blockIdx.x * 256 + threadIdx.x;
  if (i < B * HID) pooled[i] = 0.f;
}

// batch is sorted: boundary threads plain-store segment starts. No atomics.
__global__ __launch_bounds__(256) void k_seg_starts(const int* __restrict__ batch,
                                                    int* __restrict__ starts) {
  int i = blockIdx.x * 256 + threadIdx.x;
  if (i >= N) return;
  int b = batch[i];
  int prev = (i == 0) ? -1 : batch[i - 1];
  for (int g = prev + 1; g <= b; ++g) starts[g] = i;  // fires only at boundaries
  if (i == N - 1)
    for (int g = b + 1; g <= B; ++g) starts[g] = N;
}

// ---------------- CSR build: two-level bucket sort ----------------

__global__ __launch_bounds__(256) void k_hist(const int* __restrict__ eidx,
                                              int* __restrict__ hist) {
  __shared__ int h[NBUK];
  for (int i = threadIdx.x; i < NBUK; i += 256) h[i] = 0;
  __syncthreads();
  const long base = (long)blockIdx.x * EPB;
  for (int i = threadIdx.x; i < EPB; i += 256)
    atomicAdd(&h[eidx[E + base + i] >> 7], 1);
  __syncthreads();
  for (int i = threadIdx.x; i < NBUK; i += 256)
    hist[(long)blockIdx.x * NBUK + i] = h[i];
}

__global__ __launch_bounds__(256) void k_bscan(int* __restrict__ hist,
                                               int* __restrict__ btotal) {
  __shared__ int s[256];
  const int j = blockIdx.x, tid = threadIdx.x;
  int v = hist[(long)tid * NBUK + j];
  s[tid] = v;
  for (int off = 1; off < 256; off <<= 1) {
    __syncthreads();
    int x = (tid >= off) ? s[tid - off] : 0;
    __syncthreads();
    s[tid] += x;
  }
  hist[(long)tid * NBUK + j] = s[tid] - v;   // exclusive within bucket
  if (tid == 255) btotal[j] = s[255];
}

__global__ __launch_bounds__(256) void k_bktscan(const int* __restrict__ btotal,
                                                 int* __restrict__ bexcl,
                                                 int* __restrict__ rowptr) {
  __shared__ int s[256];
  int tid = threadIdx.x;
  int base = tid * 4;
  int v0 = (base + 0 < NBUK) ? btotal[base + 0] : 0;
  int v1 = (base + 1 < NBUK) ? btotal[base + 1] : 0;
  int v2 = (base + 2 < NBUK) ? btotal[base + 2] : 0;
  int v3 = (base + 3 < NBUK) ? btotal[base + 3] : 0;
  int p0 = v0, p1 = p0 + v1, p2 = p1 + v2, p3 = p2 + v3;
  s[tid] = p3;
  for (int off = 1; off < 256; off <<= 1) {
    __syncthreads();
    int x = (tid >= off) ? s[tid - off] : 0;
    __syncthreads();
    s[tid] += x;
  }
  int excl = s[tid] - p3;
  if (base + 0 < NBUK) bexcl[base + 1] = excl + p0;
  if (base + 1 < NBUK) bexcl[base + 2] = excl + p1;
  if (base + 2 < NBUK) bexcl[base + 3] = excl + p2;
  if (base + 3 < NBUK) bexcl[base + 4] = excl + p3;
  if (tid == 0) { bexcl[0] = 0; rowptr[N] = E; }
}

__global__ __launch_bounds__(256) void k_scatter(const int* __restrict__ eidx,
                                                 const int* __restrict__ hist,
                                                 const int* __restrict__ bexcl,
                                                 int* __restrict__ ebuf) {
  __shared__ int h[NBUK];
  for (int i = threadIdx.x; i < NBUK; i += 256)
    h[i] = bexcl[i] + hist[(long)blockIdx.x * NBUK + i];
  __syncthreads();
  const long base = (long)blockIdx.x * EPB;
  for (int i = threadIdx.x; i < EPB; i += 256) {
    int srcv = eidx[base + i];
    int d = eidx[E + base + i];
    int pos = atomicAdd(&h[d >> 7], 1);
    ebuf[pos] = srcv | ((d & 127) << 20);
  }
}

__global__ __launch_bounds__(256) void k_csr(const int* __restrict__ ebuf,
                                             const int* __restrict__ bexcl,
                                             int* __restrict__ rowptr,
                                             float* __restrict__ dinv,
                                             int* __restrict__ colsrc) {
  __shared__ int deg[128], s[128], cur[128];
  __shared__ int lout[BMAX];
  const int j = blockIdx.x, tid = threadIdx.x;
  const int e0 = bexcl[j], e1 = bexcl[j + 1];
  const int cnt = e1 - e0;
  if (tid < 128) deg[tid] = 0;
  __syncthreads();
  for (int i = tid; i < cnt; i += 256)
    atomicAdd(&deg[(ebuf[e0 + i] >> 20) & 127], 1);
  __syncthreads();
  int v = (tid < 128) ? deg[tid] : 0;
  if (tid < 128) s[tid] = v;
  for (int off = 1; off < 128; off <<= 1) {
    __syncthreads();
    int x = (tid < 128 && tid >= off) ? s[tid - off] : 0;
    __syncthreads();
    if (tid < 128) s[tid] += x;
  }
  __syncthreads();
  if (tid < 128) {
    int ex = s[tid] - v;
    cur[tid] = ex;
    int node = j * 128 + tid;
    if (node < N) {
      rowptr[node] = e0 + ex;
      dinv[node] = rsqrtf((float)(1 + v));   // deg includes self-loop
    }
  }
  __syncthreads();
  if (cnt <= BMAX) {
    for (int i = tid; i < cnt; i += 256) {
      int p = ebuf[e0 + i];
      int pos = atomicAdd(&cur[(p >> 20) & 127], 1);
      lout[pos] = p & 0xFFFFF;
    }
    __syncthreads();
    for (int i = tid; i < cnt; i += 256) colsrc[e0 + i] = lout[i];
  } else {  // safety fallback: direct global scatter (window still tiny -> L2)
    for (int i = tid; i < cnt; i += 256) {
      int p = ebuf[e0 + i];
      int pos = atomicAdd(&cur[(p >> 20) & 127], 1);
      colsrc[e0 + pos] = p & 0xFFFFF;
    }
  }
}

// ---------------- aggregation (atomic-free gathers) ----------------

// bf16(x * dinv) table for the 20-dim gather (4MB -> L2-resident).
__global__ __launch_bounds__(256) void k_prep20(const float* __restrict__ x,
                                                const float* __restrict__ dinv,
                                                ushort_t* __restrict__ xs16) {
  long idx = (long)blockIdx.x * 256 + threadIdx.x;
  if (idx >= (long)N * IND) return;
  int i = (int)(idx / IND);
  xs16[idx] = f2bf(x[idx] * dinv[i]);
}

// 20-dim gather over bf16 x*dinv rows: 10 threads/node, 2 channels each.
// aggx[i] = dinv[i] * (row(i) + sum_e row(src_e))   (fp32 out)
__global__ __launch_bounds__(256) void k_gather20b(const ushort_t* __restrict__ xs16,
                                                   const float* __restrict__ dinv,
                                                   const int* __restrict__ rowptr,
                                                   const int* __restrict__ colsrc,
                                                   float* __restrict__ aggx) {
  int t = threadIdx.x;
  if (t >= 250) return;
  int n = t / 10, cc = (t % 10) * 2;
  long i = (long)blockIdx.x * 25 + n;               // grid = N/25 exact
  float di = dinv[i];
  uint_t u = *(const uint_t*)(xs16 + i * IND + cc);
  float a0 = bflo(u), a1 = bfhi(u);
  int e0 = rowptr[i], e1 = rowptr[i + 1];
#pragma unroll 4
  for (int e = e0; e < e1; ++e) {
    int s = colsrc[e];
    uint_t v = *(const uint_t*)(xs16 + (long)s * IND + cc);
    a0 += bflo(v); a1 += bfhi(v);
  }
  *(float2*)&aggx[i * IND + cc] = make_float2(a0 * di, a1 * di);
}

// 128-dim gather, 16B/lane: 16 lanes/row, 4 edges per wave-iteration.
// agg[i] = dinv[i] * (row(i) + sum_e row(src_e)), rows pre-scaled by dinv[src].
__global__ __launch_bounds__(256) void k_gather128c(const ushort_t* __restrict__ h16,
                                                    const float* __restrict__ dinv,
                                                    const int* __restrict__ rowptr,
                                                    const int* __restrict__ colsrc,
                                                    float* __restrict__ agg) {
  const int lane = threadIdx.x & 63;
  const int grp = lane >> 4, l16 = lane & 15;
  const long i = (long)blockIdx.x * 4 + (threadIdx.x >> 6);   // grid = N/4 exact
  const float di = dinv[i];
  const int c = l16 * 8;
  float a0 = 0, a1 = 0, a2 = 0, a3 = 0, a4 = 0, a5 = 0, a6 = 0, a7 = 0;
  if (grp == 0) {     // self term (row already carries dinv[i])
    uint4 u = *(const uint4*)(h16 + i * HID + c);
    a0 = bflo(u.x); a1 = bfhi(u.x); a2 = bflo(u.y); a3 = bfhi(u.y);
    a4 = bflo(u.z); a5 = bfhi(u.z); a6 = bflo(u.w); a7 = bfhi(u.w);
  }
  const int e0 = rowptr[i], e1 = rowptr[i + 1];
#pragma unroll 2
  for (int e = e0; e < e1; e += 4) {
    int idx = e + grp;
    bool valid = idx < e1;
    int s = colsrc[valid ? idx : e];
    uint4 u = *(const uint4*)(h16 + (long)s * HID + c);
    if (valid) {
      a0 += bflo(u.x); a1 += bfhi(u.x); a2 += bflo(u.y); a3 += bfhi(u.y);
      a4 += bflo(u.z); a5 += bfhi(u.z); a6 += bflo(u.w); a7 += bfhi(u.w);
    }
  }
  a0 += __shfl_xor(a0, 16); a0 += __shfl_xor(a0, 32);
  a1 += __shfl_xor(a1, 16); a1 += __shfl_xor(a1, 32);
  a2 += __shfl_xor(a2, 16); a2 += __shfl_xor(a2, 32);
  a3 += __shfl_xor(a3, 16); a3 += __shfl_xor(a3, 32);
  a4 += __shfl_xor(a4, 16); a4 += __shfl_xor(a4, 32);
  a5 += __shfl_xor(a5, 16); a5 += __shfl_xor(a5, 32);
  a6 += __shfl_xor(a6, 16); a6 += __shfl_xor(a6, 32);
  a7 += __shfl_xor(a7, 16); a7 += __shfl_xor(a7, 32);
  if (grp == 0) {
    *(float4*)&agg[i * HID + c]     = make_float4(a0 * di, a1 * di, a2 * di, a3 * di);
    *(float4*)&agg[i * HID + c + 4] = make_float4(a4 * di, a5 * di, a6 * di, a7 * di);
  }
}

// Layer-3 gather fused with mean-pool accumulation: no agg write.
// Block = 4 consecutive nodes (batch-sorted -> usually one graph).
__global__ __launch_bounds__(256) void k_gather128p(const ushort_t* __restrict__ h16,
                                                    const float* __restrict__ dinv,
                                                    const int* __restrict__ rowptr,
                                                    const int* __restrict__ colsrc,
                                                    const int* __restrict__ batch,
                                                    float* __restrict__ pooled) {
  __shared__ float sacc[4][HID];
  __shared__ int sg[4];
  const int lane = threadIdx.x & 63;
  const int grp = lane >> 4, l16 = lane & 15;
  const int w = threadIdx.x >> 6;
  const long i = (long)blockIdx.x * 4 + w;                    // grid = N/4 exact
  const float di = dinv[i];
  const int c = l16 * 8;
  float a0 = 0, a1 = 0, a2 = 0, a3 = 0, a4 = 0, a5 = 0, a6 = 0, a7 = 0;
  if (grp == 0) {
    uint4 u = *(const uint4*)(h16 + i * HID + c);
    a0 = bflo(u.x); a1 = bfhi(u.x); a2 = bflo(u.y); a3 = bfhi(u.y);
    a4 = bflo(u.z); a5 = bfhi(u.z); a6 = bflo(u.w); a7 = bfhi(u.w);
  }
  const int e0 = rowptr[i], e1 = rowptr[i + 1];
#pragma unroll 2
  for (int e = e0; e < e1; e += 4) {
    int idx = e + grp;
    bool valid = idx < e1;
    int s = colsrc[valid ? idx : e];
    uint4 u = *(const uint4*)(h16 + (long)s * HID + c);
    if (valid) {
      a0 += bflo(u.x); a1 += bfhi(u.x); a2 += bflo(u.y); a3 += bfhi(u.y);
      a4 += bflo(u.z); a5 += bfhi(u.z); a6 += bflo(u.w); a7 += bfhi(u.w);
    }
  }
  a0 += __shfl_xor(a0, 16); a0 += __shfl_xor(a0, 32);
  a1 += __shfl_xor(a1, 16); a1 += __shfl_xor(a1, 32);
  a2 += __shfl_xor(a2, 16); a2 += __shfl_xor(a2, 32);
  a3 += __shfl_xor(a3, 16); a3 += __shfl_xor(a3, 32);
  a4 += __shfl_xor(a4, 16); a4 += __shfl_xor(a4, 32);
  a5 += __shfl_xor(a5, 16); a5 += __shfl_xor(a5, 32);
  a6 += __shfl_xor(a6, 16); a6 += __shfl_xor(a6, 32);
  a7 += __shfl_xor(a7, 16); a7 += __shfl_xor(a7, 32);
  if (grp == 0) {
    *(float4*)&sacc[w][c]     = make_float4(a0 * di, a1 * di, a2 * di, a3 * di);
    *(float4*)&sacc[w][c + 4] = make_float4(a4 * di, a5 * di, a6 * di, a7 * di);
    if (l16 == 0) sg[w] = batch[i];
  }
  __syncthreads();
  if (threadIdx.x < HID) {
    int j = threadIdx.x;
    int g0 = sg[0];
    if (sg[1] == g0 && sg[2] == g0 && sg[3] == g0) {
      atomicAdd(&pooled[g0 * HID + j],
                sacc[0][j] + sacc[1][j] + sacc[2][j] + sacc[3][j]);
    } else {
#pragma unroll
      for (int w2 = 0; w2 < 4; ++w2)
        atomicAdd(&pooled[sg[w2] * HID + j], sacc[w2][j]);
    }
  }
}

// ---------------- dense layers ----------------

// T = aggx@W1 + b1 + x@res_W + res_b   (pre-LN1 sum), 16 nodes / block
__global__ __launch_bounds__(128) void k_conv1(const float* __restrict__ aggx,
                                               const float* __restrict__ x,
                                               const float* __restrict__ W1,
                                               const float* __restrict__ b1,
                                               const float* __restrict__ Wr,
                                               const float* __restrict__ rb,
                                               float* __restrict__ T) {
  __shared__ float W1s[IND * HID], Wrs[IND * HID], as[16 * IND], xs[16 * IND];
  int tid = threadIdx.x;
  for (int i = tid; i < IND * HID; i += 128) { W1s[i] = W1[i]; Wrs[i] = Wr[i]; }
  long node0 = (long)blockIdx.x * 16;                 // grid = N/16 exact
  for (int i = tid; i < 16 * IND; i += 128) {
    as[i] = aggx[node0 * IND + i];
    xs[i] = x[node0 * IND + i];
  }
  float bj = b1[tid] + rb[tid];
  __syncthreads();
  for (int n = 0; n < 16; ++n) {
    float a = bj;
#pragma unroll
    for (int k = 0; k < IND; ++k) {
      a = fmaf(as[n * IND + k], W1s[k * HID + tid], a);
      a = fmaf(xs[n * IND + k], Wrs[k * HID + tid], a);
    }
    T[(node0 + n) * HID + tid] = a;
  }
}

// out = in@W + bias + res   (128x128, K-tiled in LDS, 32 nodes / block, in-place safe)
__global__ __launch_bounds__(256) void k_gemm128(const float* in,
                                                 const float* __restrict__ W,
                                                 const float* __restrict__ bias,
                                                 const float* __restrict__ res,
                                                 float* out) {
  constexpr int NPB = 32;
  __shared__ float Wt[32 * HID];
  __shared__ float Xs[NPB * HID];
  const int tid = threadIdx.x;
  const long node0 = (long)blockIdx.x * NPB;          // grid = N/32 exact
  {
    const float4* sp = (const float4*)(in + node0 * HID);
    float4* dp = (float4*)Xs;
    for (int i = tid; i < NPB * HID / 4; i += 256) dp[i] = sp[i];
  }
  const int nidx = tid >> 5;          // 8 nodes in flight
  const int col = (tid & 31) * 4;     // 32 threads cover 128 cols
  float4 acc[4];
#pragma unroll
  for (int m = 0; m < 4; ++m) acc[m] = make_float4(0.f, 0.f, 0.f, 0.f);
  for (int kt = 0; kt < 4; ++kt) {
    __syncthreads();
    {
      const float4* wp = (const float4*)(W + kt * 32 * HID);
      float4* wd = (float4*)Wt;
      for (int i = tid; i < 32 * HID / 4; i += 256) wd[i] = wp[i];
    }
    __syncthreads();
#pragma unroll
    for (int k = 0; k < 32; k += 4) {
      float4 w[4];
#pragma unroll
      for (int kk = 0; kk < 4; ++kk) w[kk] = *(const float4*)&Wt[(k + kk) * HID + col];
#pragma unroll
      for (int m = 0; m < 4; ++m) {
        const int nm = nidx + m * 8;
        float4 x4 = *(const float4*)&Xs[nm * HID + kt * 32 + k];
        float xv[4] = {x4.x, x4.y, x4.z, x4.w};
#pragma unroll
        for (int kk = 0; kk < 4; ++kk) {
          acc[m].x = fmaf(xv[kk], w[kk].x, acc[m].x);
          acc[m].y = fmaf(xv[kk], w[kk].y, acc[m].y);
          acc[m].z = fmaf(xv[kk], w[kk].z, acc[m].z);
          acc[m].w = fmaf(xv[kk], w[kk].w, acc[m].w);
        }
      }
    }
  }
  float4 bz = *(const float4*)&bias[col];
#pragma unroll
  for (int m = 0; m < 4; ++m) {
    long nm = node0 + nidx + m * 8;
    float4 rz = *(const float4*)&res[nm * HID + col];
    float4 o = acc[m];
    o.x += bz.x + rz.x; o.y += bz.y + rz.y;
    o.z += bz.z + rz.z; o.w += bz.w + rz.w;
    *(float4*)&out[nm * HID + col] = o;
  }
}

// relu(layernorm(in)): optional fp32 out (residual path) + bf16 out scaled by
// dinv[i] (gather payload). One wave per node.
__global__ __launch_bounds__(256) void k_lnrelu(const float* __restrict__ in,
                                                const float* __restrict__ g,
                                                const float* __restrict__ b,
                                                const float* __restrict__ dinv,
                                                float* __restrict__ outf,
                                                ushort_t* __restrict__ out16) {
  const int lane = threadIdx.x & 63;
  const long i = (long)blockIdx.x * 4 + (threadIdx.x >> 6);   // grid = N/4 exact
  const int c = lane * 2;
  float2 v = *(const float2*)&in[i * HID + c];
  float s = v.x + v.y, q = v.x * v.x + v.y * v.y;
#pragma unroll
  for (int off = 32; off; off >>= 1) {
    s += __shfl_xor(s, off);
    q += __shfl_xor(q, off);
  }
  const float mu = s * (1.f / 128.f);
  const float var = q * (1.f / 128.f) - mu * mu;
  const float rs = rsqrtf(var + 1e-5f);
  float2 gg = *(const float2*)&g[c], bb = *(const float2*)&b[c];
  float y0 = fmaxf(fmaf((v.x - mu) * rs, gg.x, bb.x), 0.f);
  float y1 = fmaxf(fmaf((v.y - mu) * rs, gg.y, bb.y), 0.f);
  if (outf) *(float2*)&outf[i * HID + c] = make_float2(y0, y1);
  const float di = dinv[i];
  ushort_t p0 = f2bf(y0 * di), p1 = f2bf(y1 * di);
  *(uint_t*)&out16[i * HID + c] = (uint_t)p0 | ((uint_t)p1 << 16);
}

// ---------------- final GEMM ----------------

// out[g] = (pooled[g]/cnt) @ W3 + b3
__global__ __launch_bounds__(256) void k_final(const float* __restrict__ pooled,
                                               const int* __restrict__ starts,
                                               const float* __restrict__ W3,
                                               const float* __restrict__ b3,
                                               float* __restrict__ out) {
  __shared__ float p[HID];
  int g = blockIdx.x, tid = threadIdx.x;
  int len = starts[g + 1] - starts[g];
  float scale = 1.0f / fmaxf((float)len, 1.0f);
  if (tid < HID) p[tid] = pooled[g * HID + tid] * scale;
  __syncthreads();
  float a = b3[tid];
  for (int k = 0; k < HID; ++k) a = fmaf(p[k], W3[k * OUTD + tid], a);
  out[g * OUTD + tid] = a;
}

// ---------------- launch ----------------

extern "C" void kernel_launch(void* const* d_in, const int* in_sizes, int n_in,
                              void* d_out, int out_size, void* d_ws, size_t ws_size,
                              hipStream_t stream) {
  const float* x    = (const float*)d_in[0];
  const int*   eidx = (const int*)d_in[1];
  const int*   batch= (const int*)d_in[2];
  const float* W1   = (const float*)d_in[3];
  const float* b1   = (const float*)d_in[4];
  const float* W2   = (const float*)d_in[5];
  const float* b2   = (const float*)d_in[6];
  const float* W3   = (const float*)d_in[7];
  const float* b3   = (const float*)d_in[8];
  const float* resW = (const float*)d_in[9];
  const float* resb = (const float*)d_in[10];
  const float* g1   = (const float*)d_in[11];
  const float* bb1  = (const float*)d_in[12];
  const float* g2   = (const float*)d_in[13];
  const float* bb2  = (const float*)d_in[14];
  float* out = (float*)d_out;

  char* w = (char*)d_ws;
  size_t off = 0;
  auto alloc = [&](size_t bytes) {
    char* p = w + off;
    off = (off + bytes + 1023) & ~(size_t)1023;
    return p;
  };
  float* dinv   = (float*)alloc((size_t)N * 4);
  int*   rowptr = (int*)alloc((size_t)(N + 1) * 4);
  int*   colsrc = (int*)alloc((size_t)E * 4);
  int*   ebuf   = (int*)alloc((size_t)E * 4);
  int*   hist   = (int*)alloc((size_t)GB * NBUK * 4);
  int*   btotal = (int*)alloc((size_t)NBUK * 4);
  int*   bexcl  = (int*)alloc((size_t)(NBUK + 1) * 4);
  int*   starts = (int*)alloc((size_t)(B + 1) * 4);
  float* pooled = (float*)alloc((size_t)B * HID * 4);
  float* aggx   = (float*)alloc((size_t)N * IND * 4);
  float* hbuf   = (float*)alloc((size_t)N * HID * 4);
  float* aggh   = (float*)alloc((size_t)N * HID * 4);
  ushort_t* h16 = (ushort_t*)alloc((size_t)N * HID * 2);
  ushort_t* xs16= (ushort_t*)alloc((size_t)N * IND * 2);

  // ---- CSR (bucket sort) + norm + segment starts ----
  k_init<<<(B * HID + 255) / 256, 256, 0, stream>>>(pooled);
  k_seg_starts<<<(N + 255) / 256, 256, 0, stream>>>(batch, starts);
  k_hist<<<GB, 256, 0, stream>>>(eidx, hist);
  k_bscan<<<NBUK, 256, 0, stream>>>(hist, btotal);
  k_bktscan<<<1, 256, 0, stream>>>(btotal, bexcl, rowptr);
  k_scatter<<<GB, 256, 0, stream>>>(eidx, hist, bexcl, ebuf);
  k_csr<<<NBUK, 256, 0, stream>>>(ebuf, bexcl, rowptr, dinv, colsrc);

  // ---- layer 1: aggregate x (20-dim, bf16 table), transform, LN+relu ----
  k_prep20<<<(N * IND + 255) / 256, 256, 0, stream>>>(x, dinv, xs16);
  k_gather20b<<<N / 25, 256, 0, stream>>>(xs16, dinv, rowptr, colsrc, aggx);
  k_conv1<<<N / 16, 128, 0, stream>>>(aggx, x, W1, b1, resW, resb, aggh);
  k_lnrelu<<<N / 4, 256, 0, stream>>>(aggh, g1, bb1, dinv, hbuf, h16);  // h1 fp32+bf16

  // ---- layer 2: aggregate h1 (bf16), GEMM(+b2+residual h1) in-place, LN+relu ----
  k_gather128c<<<N / 4, 256, 0, stream>>>(h16, dinv, rowptr, colsrc, aggh);
  k_gemm128<<<N / 32, 256, 0, stream>>>(aggh, W2, b2, hbuf, aggh);
  k_lnrelu<<<N / 4, 256, 0, stream>>>(aggh, g2, bb2, dinv, nullptr, h16); // h2 bf16 only

  // ---- layer 3: aggregate h2 fused with mean-pool, then tiny GEMM to 256 ----
  k_gather128p<<<N / 4, 256, 0, stream>>>(h16, dinv, rowptr, colsrc, batch, pooled);
  k_final<<<B, 256, 0, stream>>>(pooled, starts, W3, b3, out);
}